// Round 2
// baseline (588.442 us; speedup 1.0000x reference)
//
#include <hip/hip_runtime.h>
#include <hip/hip_bf16.h>

#define N_NODES 8192
#define IN_DIM  256
#define HID     512
#define NCLS    256
#define CAP     128   // max in-degree capacity (mean 32, sigma ~5.7; 128 is ~17 sigma)

typedef __attribute__((ext_vector_type(8))) __bf16 bf16x8;
typedef __attribute__((ext_vector_type(4))) float  floatx4;

static __device__ __forceinline__ float bf2f(ushort u) {
    union { float f; unsigned int i; } v; v.i = ((unsigned int)u) << 16; return v.f;
}
static __device__ __forceinline__ ushort f2bf(float f) {
    __hip_bfloat16 b = __float2bfloat16(f);   // round-to-nearest
    return *reinterpret_cast<ushort*>(&b);
}

// ---------------------------------------------------------------------------
// K1: scan A (fp32 binary, row-major [i][j]) -> per-column neighbor lists.
// col j collects {i : A[i,j] != 0}. Coalesced float4 loads (4 cols/thread).
// Grid: (8 col-groups of 1024, 128 row-chunks of 64). List order is
// nondeterministic (atomic append) but all sums over it are order-free.
// ---------------------------------------------------------------------------
__global__ __launch_bounds__(256) void build_csc(const float* __restrict__ A,
                                                 int* __restrict__ col_cnt,
                                                 int* __restrict__ col_idx) {
    const int jbase = (blockIdx.x * 256 + threadIdx.x) * 4;
    const int i0 = blockIdx.y * 64;
    for (int ii = 0; ii < 64; ++ii) {
        const int i = i0 + ii;
        float4 v = *reinterpret_cast<const float4*>(A + (size_t)i * N_NODES + jbase);
        if (v.x != 0.0f) { int p = atomicAdd(&col_cnt[jbase + 0], 1); if (p < CAP) col_idx[(size_t)(jbase + 0) * CAP + p] = i; }
        if (v.y != 0.0f) { int p = atomicAdd(&col_cnt[jbase + 1], 1); if (p < CAP) col_idx[(size_t)(jbase + 1) * CAP + p] = i; }
        if (v.z != 0.0f) { int p = atomicAdd(&col_cnt[jbase + 2], 1); if (p < CAP) col_idx[(size_t)(jbase + 2) * CAP + p] = i; }
        if (v.w != 0.0f) { int p = atomicAdd(&col_cnt[jbase + 3], 1); if (p < CAP) col_idx[(size_t)(jbase + 3) * CAP + p] = i; }
    }
}

// K2: dis[j] = rsqrt(deg_j), deg = colsum(A) + 1 (self loop)
__global__ __launch_bounds__(256) void compute_dis(const int* __restrict__ col_cnt,
                                                   float* __restrict__ dis) {
    const int j = blockIdx.x * 256 + threadIdx.x;
    dis[j] = rsqrtf((float)col_cnt[j] + 1.0f);
}

// K3a: split x (fp32) into bf16 hi + bf16 residual-lo.
__global__ __launch_bounds__(256) void split_x(const float* __restrict__ in,
                                               ushort* __restrict__ hi,
                                               ushort* __restrict__ lo) {
    const int i = blockIdx.x * 256 + threadIdx.x;
    const float v = in[i];
    const ushort h = f2bf(v);
    hi[i] = h;
    lo[i] = f2bf(v - bf2f(h));
}

// K3b: transpose + split weights. W1 [256,512] -> W1T{h,l} [512,256];
// W2 [512,256] -> W2T{h,l} [256,512]. Contiguous-k rows for MFMA B-frags.
__global__ __launch_bounds__(256) void prep_w(const float* __restrict__ W1,
                                              const float* __restrict__ W2,
                                              ushort* __restrict__ W1Th, ushort* __restrict__ W1Tl,
                                              ushort* __restrict__ W2Th, ushort* __restrict__ W2Tl) {
    const int idx = blockIdx.x * 256 + threadIdx.x;   // < 131072
    {
        const int k = idx / HID, n = idx % HID;
        const float v = W1[idx]; const ushort h = f2bf(v);
        W1Th[(size_t)n * IN_DIM + k] = h;
        W1Tl[(size_t)n * IN_DIM + k] = f2bf(v - bf2f(h));
    }
    {
        const int k = idx / NCLS, n = idx % NCLS;
        const float v = W2[idx]; const ushort h = f2bf(v);
        W2Th[(size_t)n * HID + k] = h;
        W2Tl[(size_t)n * HID + k] = f2bf(v - bf2f(h));
    }
}

// ---------------------------------------------------------------------------
// K4: C[M,N] fp32 = (Ah+Al)[M,K] @ (Bh+Bl)[N,K]^T via 3-product split-bf16:
//     C = Ah@Bh + Ah@Bl + Al@Bh   (Al@Bl ~ 2^-18 rel, dropped)
// 16x16x32 MFMA. Block = 4 waves (2x2), wave tile 64x64, block tile 128x128.
// A-frag: A[m = lane&15][k0 + (lane>>4)*8 + 0..7]  (16B vector load)
// C/D:    row = (lane>>4)*4 + reg, col = lane&15   (verified m89/m91 layout)
// ---------------------------------------------------------------------------
__global__ __launch_bounds__(256) void gemm_split(const ushort* __restrict__ Ah,
                                                  const ushort* __restrict__ Al,
                                                  const ushort* __restrict__ Bh,
                                                  const ushort* __restrict__ Bl,
                                                  float* __restrict__ C,
                                                  int M, int N, int K) {
    const int tid  = threadIdx.x;
    const int lane = tid & 63, wave = tid >> 6;
    const int wm = wave >> 1, wn = wave & 1;
    const int l16 = lane & 15, quad = lane >> 4;
    const int m_base = blockIdx.x * 128 + wm * 64;
    const int n_base = blockIdx.y * 128 + wn * 64;

    floatx4 acc[4][4] = {};
    for (int k0 = 0; k0 < K; k0 += 32) {
        const int kf = k0 + quad * 8;
        bf16x8 ah[4], al[4], bh[4], bl[4];
#pragma unroll
        for (int t = 0; t < 4; ++t) {
            const size_t ao = (size_t)(m_base + t * 16 + l16) * K + kf;
            ah[t] = *reinterpret_cast<const bf16x8*>(Ah + ao);
            al[t] = *reinterpret_cast<const bf16x8*>(Al + ao);
        }
#pragma unroll
        for (int t = 0; t < 4; ++t) {
            const size_t bo = (size_t)(n_base + t * 16 + l16) * K + kf;
            bh[t] = *reinterpret_cast<const bf16x8*>(Bh + bo);
            bl[t] = *reinterpret_cast<const bf16x8*>(Bl + bo);
        }
#pragma unroll
        for (int tm = 0; tm < 4; ++tm)
#pragma unroll
            for (int tn = 0; tn < 4; ++tn) {
                acc[tm][tn] = __builtin_amdgcn_mfma_f32_16x16x32_bf16(ah[tm], bl[tn], acc[tm][tn], 0, 0, 0);
                acc[tm][tn] = __builtin_amdgcn_mfma_f32_16x16x32_bf16(al[tm], bh[tn], acc[tm][tn], 0, 0, 0);
                acc[tm][tn] = __builtin_amdgcn_mfma_f32_16x16x32_bf16(ah[tm], bh[tn], acc[tm][tn], 0, 0, 0);
            }
    }
#pragma unroll
    for (int tm = 0; tm < 4; ++tm)
#pragma unroll
        for (int tn = 0; tn < 4; ++tn)
#pragma unroll
            for (int r = 0; r < 4; ++r)
                C[(size_t)(m_base + tm * 16 + quad * 4 + r) * N + (n_base + tn * 16 + l16)] = acc[tm][tn][r];
}

// ---------------------------------------------------------------------------
// K5: layer-1 aggregation + bias + relu -> split bf16 h (GEMM2 A-operand).
// h[j] = relu(dis_j * (sum_{i in N(j)} dis_i*g1[i] + dis_j*g1[j]) + b1)
// One block per node; 256 threads x float2 over 512 features (coalesced).
// ---------------------------------------------------------------------------
__global__ __launch_bounds__(256) void agg_relu_1(const float* __restrict__ g1,
                                                  const int* __restrict__ col_idx,
                                                  const int* __restrict__ col_cnt,
                                                  const float* __restrict__ dis,
                                                  const float* __restrict__ b1,
                                                  ushort* __restrict__ h_hi,
                                                  ushort* __restrict__ h_lo) {
    const int j = blockIdx.x;
    const int d = threadIdx.x * 2;
    const float dj = dis[j];
    const float2 self = *reinterpret_cast<const float2*>(g1 + (size_t)j * HID + d);
    float ax = dj * self.x, ay = dj * self.y;
    const int cnt = min(col_cnt[j], CAP);
    const int* __restrict__ lst = col_idx + (size_t)j * CAP;
    for (int e = 0; e < cnt; ++e) {
        const int i = lst[e];
        const float di = dis[i];
        const float2 v = *reinterpret_cast<const float2*>(g1 + (size_t)i * HID + d);
        ax += di * v.x; ay += di * v.y;
    }
    const float hx = fmaxf(dj * ax + b1[d],     0.0f);
    const float hy = fmaxf(dj * ay + b1[d + 1], 0.0f);
    const ushort hxh = f2bf(hx), hyh = f2bf(hy);
    h_hi[(size_t)j * HID + d]     = hxh;
    h_hi[(size_t)j * HID + d + 1] = hyh;
    h_lo[(size_t)j * HID + d]     = f2bf(hx - bf2f(hxh));
    h_lo[(size_t)j * HID + d + 1] = f2bf(hy - bf2f(hyh));
}

// K6: layer-2 aggregation + bias + skip + scaled sigmoid -> fp32 out.
__global__ __launch_bounds__(256) void agg_out(const float* __restrict__ g2,
                                               const int* __restrict__ col_idx,
                                               const int* __restrict__ col_cnt,
                                               const float* __restrict__ dis,
                                               const float* __restrict__ b2,
                                               const float* __restrict__ x,
                                               const float* __restrict__ sp_p,
                                               float* __restrict__ out) {
    const int j = blockIdx.x;
    const int d = threadIdx.x;
    const float dj = dis[j];
    float acc = dj * g2[(size_t)j * NCLS + d];
    const int cnt = min(col_cnt[j], CAP);
    const int* __restrict__ lst = col_idx + (size_t)j * CAP;
    for (int e = 0; e < cnt; ++e) {
        const int i = lst[e];
        acc += dis[i] * g2[(size_t)i * NCLS + d];
    }
    const float sp = sp_p[0];
    const float val = dj * acc + b2[d] + x[(size_t)j * NCLS + d];
    out[(size_t)j * NCLS + d] = 1.0f / (1.0f + __expf(-sp * val));
}

extern "C" void kernel_launch(void* const* d_in, const int* in_sizes, int n_in,
                              void* d_out, int out_size, void* d_ws, size_t ws_size,
                              hipStream_t stream) {
    const float* A  = (const float*)d_in[0];   // [8192,8192] fp32 (0.0/1.0)
    const float* x  = (const float*)d_in[1];   // [8192,256]  fp32
    const float* W1 = (const float*)d_in[2];   // [256,512]   fp32
    const float* b1 = (const float*)d_in[3];   // [512]       fp32
    const float* W2 = (const float*)d_in[4];   // [512,256]   fp32
    const float* b2 = (const float*)d_in[5];   // [256]       fp32
    const float* sp = (const float*)d_in[6];   // [1]         fp32
    float* out = (float*)d_out;                // [8192,256]  fp32

    char* ws = (char*)d_ws;
    size_t off = 0;
    auto alloc = [&](size_t bytes) {
        void* p = ws + off;
        off = (off + bytes + 255) & ~(size_t)255;
        return p;
    };
    int*    col_cnt = (int*)   alloc((size_t)N_NODES * 4);
    float*  dis     = (float*) alloc((size_t)N_NODES * 4);
    int*    col_idx = (int*)   alloc((size_t)N_NODES * CAP * 4);     // 4 MB
    ushort* x_hi    = (ushort*)alloc((size_t)N_NODES * IN_DIM * 2);  // 4 MB
    ushort* x_lo    = (ushort*)alloc((size_t)N_NODES * IN_DIM * 2);  // 4 MB
    ushort* W1Th    = (ushort*)alloc((size_t)HID * IN_DIM * 2);
    ushort* W1Tl    = (ushort*)alloc((size_t)HID * IN_DIM * 2);
    ushort* W2Th    = (ushort*)alloc((size_t)NCLS * HID * 2);
    ushort* W2Tl    = (ushort*)alloc((size_t)NCLS * HID * 2);
    float*  g1      = (float*) alloc((size_t)N_NODES * HID * 4);     // 16 MB
    ushort* h_hi    = (ushort*)alloc((size_t)N_NODES * HID * 2);     // 8 MB
    ushort* h_lo    = (ushort*)alloc((size_t)N_NODES * HID * 2);     // 8 MB
    float*  g2      = (float*) alloc((size_t)N_NODES * NCLS * 4);    // 8 MB

    hipMemsetAsync(col_cnt, 0, (size_t)N_NODES * 4, stream);

    build_csc<<<dim3(8, 128), 256, 0, stream>>>(A, col_cnt, col_idx);
    compute_dis<<<N_NODES / 256, 256, 0, stream>>>(col_cnt, dis);
    split_x<<<(N_NODES * IN_DIM) / 256, 256, 0, stream>>>(x, x_hi, x_lo);
    prep_w<<<(IN_DIM * HID) / 256, 256, 0, stream>>>(W1, W2, W1Th, W1Tl, W2Th, W2Tl);

    // GEMM1: g1 = x @ W1   (M=8192, N=512, K=256)
    gemm_split<<<dim3(N_NODES / 128, HID / 128), 256, 0, stream>>>(
        x_hi, x_lo, W1Th, W1Tl, g1, N_NODES, HID, IN_DIM);
    agg_relu_1<<<N_NODES, 256, 0, stream>>>(g1, col_idx, col_cnt, dis, b1, h_hi, h_lo);

    // GEMM2: g2 = h @ W2   (M=8192, N=256, K=512)
    gemm_split<<<dim3(N_NODES / 128, NCLS / 128), 256, 0, stream>>>(
        h_hi, h_lo, W2Th, W2Tl, g2, N_NODES, NCLS, HID);
    agg_out<<<N_NODES, 256, 0, stream>>>(g2, col_idx, col_cnt, dis, b2, x, sp, out);
}

// Round 3
// 502.375 us; speedup vs baseline: 1.1713x; 1.1713x over previous
//
#include <hip/hip_runtime.h>
#include <hip/hip_bf16.h>

#define N_NODES 8192
#define IN_DIM  256
#define HID     512
#define NCLS    256
#define CAP     128   // max in-degree capacity (Poisson mean 32; 128 is safe)

typedef __attribute__((ext_vector_type(8))) __bf16 bf16x8;
typedef __attribute__((ext_vector_type(4))) float  floatx4;

static __device__ __forceinline__ float bf2f(ushort u) {
    union { float f; unsigned int i; } v; v.i = ((unsigned int)u) << 16; return v.f;
}
static __device__ __forceinline__ ushort f2bf(float f) {
    __hip_bfloat16 b = __float2bfloat16(f);   // round-to-nearest
    return *reinterpret_cast<ushort*>(&b);
}

// ---------------------------------------------------------------------------
// K1: scan A (fp32 binary, row-major [i][j]) -> per-column neighbor lists.
// Coalesced float4 loads, 4 cols/thread. Grid (8, 256): 2048 blocks, 32 rows
// each -> 8 blocks/CU for HBM saturation. List order nondeterministic
// (atomic append) but all downstream sums are order-free.
// ---------------------------------------------------------------------------
__global__ __launch_bounds__(256) void build_csc(const float* __restrict__ A,
                                                 int* __restrict__ col_cnt,
                                                 int* __restrict__ col_idx) {
    const int jbase = (blockIdx.x * 256 + threadIdx.x) * 4;
    const int i0 = blockIdx.y * 32;
    for (int ii = 0; ii < 32; ++ii) {
        const int i = i0 + ii;
        float4 v = *reinterpret_cast<const float4*>(A + (size_t)i * N_NODES + jbase);
        if (v.x != 0.0f) { int p = atomicAdd(&col_cnt[jbase + 0], 1); if (p < CAP) col_idx[(size_t)(jbase + 0) * CAP + p] = i; }
        if (v.y != 0.0f) { int p = atomicAdd(&col_cnt[jbase + 1], 1); if (p < CAP) col_idx[(size_t)(jbase + 1) * CAP + p] = i; }
        if (v.z != 0.0f) { int p = atomicAdd(&col_cnt[jbase + 2], 1); if (p < CAP) col_idx[(size_t)(jbase + 2) * CAP + p] = i; }
        if (v.w != 0.0f) { int p = atomicAdd(&col_cnt[jbase + 3], 1); if (p < CAP) col_idx[(size_t)(jbase + 3) * CAP + p] = i; }
    }
}

// K2: transpose + split weights into bf16 hi/lo residual pairs.
// W1 [256,512] -> W1T{h,l} [512,256]; W2 [512,256] -> W2T{h,l} [256,512].
__global__ __launch_bounds__(256) void prep_w(const float* __restrict__ W1,
                                              const float* __restrict__ W2,
                                              ushort* __restrict__ W1Th, ushort* __restrict__ W1Tl,
                                              ushort* __restrict__ W2Th, ushort* __restrict__ W2Tl) {
    const int idx = blockIdx.x * 256 + threadIdx.x;   // < 131072
    {
        const int k = idx / HID, n = idx % HID;
        const float v = W1[idx]; const ushort h = f2bf(v);
        W1Th[(size_t)n * IN_DIM + k] = h;
        W1Tl[(size_t)n * IN_DIM + k] = f2bf(v - bf2f(h));
    }
    {
        const int k = idx / NCLS, n = idx % NCLS;
        const float v = W2[idx]; const ushort h = f2bf(v);
        W2Th[(size_t)n * HID + k] = h;
        W2Tl[(size_t)n * HID + k] = f2bf(v - bf2f(h));
    }
}

// ---------------------------------------------------------------------------
// K3: layer-1 aggregation FIRST (P commutes with the feature GEMM):
// px[j] = dis_j * (sum_{i in N(j)} dis_i * x[i] + dis_j * x[j])
// Output directly as split bf16 (GEMM1 A-operand). One block per node,
// 256 threads x 1 float over IN_DIM=256 (coalesced 1 KB row reads).
// dis folded in as rsqrtf(col_cnt+1). 4-way unroll for loads in flight.
// ---------------------------------------------------------------------------
__global__ __launch_bounds__(256) void agg_x(const float* __restrict__ x,
                                             const int* __restrict__ col_idx,
                                             const int* __restrict__ col_cnt,
                                             ushort* __restrict__ px_hi,
                                             ushort* __restrict__ px_lo) {
    const int j = blockIdx.x;
    const int d = threadIdx.x;
    const int cntj = min(col_cnt[j], CAP);
    const float dj = rsqrtf((float)col_cnt[j] + 1.0f);
    float acc = dj * x[(size_t)j * IN_DIM + d];     // self-loop term (x dj below)
    const int* __restrict__ lst = col_idx + (size_t)j * CAP;
    int e = 0;
    for (; e + 3 < cntj; e += 4) {
        const int i0 = lst[e], i1 = lst[e + 1], i2 = lst[e + 2], i3 = lst[e + 3];
        const float d0 = rsqrtf((float)col_cnt[i0] + 1.0f);
        const float d1 = rsqrtf((float)col_cnt[i1] + 1.0f);
        const float d2 = rsqrtf((float)col_cnt[i2] + 1.0f);
        const float d3 = rsqrtf((float)col_cnt[i3] + 1.0f);
        const float v0 = x[(size_t)i0 * IN_DIM + d];
        const float v1 = x[(size_t)i1 * IN_DIM + d];
        const float v2 = x[(size_t)i2 * IN_DIM + d];
        const float v3 = x[(size_t)i3 * IN_DIM + d];
        acc += d0 * v0 + d1 * v1 + d2 * v2 + d3 * v3;
    }
    for (; e < cntj; ++e) {
        const int i = lst[e];
        acc += rsqrtf((float)col_cnt[i] + 1.0f) * x[(size_t)i * IN_DIM + d];
    }
    acc *= dj;
    const ushort hi = f2bf(acc);
    px_hi[(size_t)j * IN_DIM + d] = hi;
    px_lo[(size_t)j * IN_DIM + d] = f2bf(acc - bf2f(hi));
}

// ---------------------------------------------------------------------------
// Shared GEMM core: acc[4][2] += (Ah+Al)[M,K] @ (Bh+Bl)[N,K]^T, split-bf16
// 3-product (Ah@Bh + Ah@Bl + Al@Bh; Al@Bl ~2^-18 dropped). 16x16x32 MFMA.
// Block = 4 waves (2 M x 2 N), wave tile 64x32, block tile 128x64.
// A-frag: A[m = lane&15][k0 + (lane>>4)*8 + 0..7]  (16B vector load)
// C/D:    row = (lane>>4)*4 + reg, col = lane&15   (verified layout)
// ---------------------------------------------------------------------------
__device__ __forceinline__ void gemm_core(const ushort* __restrict__ Ah,
                                          const ushort* __restrict__ Al,
                                          const ushort* __restrict__ Bh,
                                          const ushort* __restrict__ Bl,
                                          int K, int m_base, int n_base,
                                          int l16, int quad, floatx4 acc[4][2]) {
    for (int k0 = 0; k0 < K; k0 += 32) {
        const int kf = k0 + quad * 8;
        bf16x8 ah[4], al[4], bh[2], bl[2];
#pragma unroll
        for (int t = 0; t < 4; ++t) {
            const size_t ao = (size_t)(m_base + t * 16 + l16) * K + kf;
            ah[t] = *reinterpret_cast<const bf16x8*>(Ah + ao);
            al[t] = *reinterpret_cast<const bf16x8*>(Al + ao);
        }
#pragma unroll
        for (int t = 0; t < 2; ++t) {
            const size_t bo = (size_t)(n_base + t * 16 + l16) * K + kf;
            bh[t] = *reinterpret_cast<const bf16x8*>(Bh + bo);
            bl[t] = *reinterpret_cast<const bf16x8*>(Bl + bo);
        }
#pragma unroll
        for (int tm = 0; tm < 4; ++tm)
#pragma unroll
            for (int tn = 0; tn < 2; ++tn) {
                acc[tm][tn] = __builtin_amdgcn_mfma_f32_16x16x32_bf16(ah[tm], bl[tn], acc[tm][tn], 0, 0, 0);
                acc[tm][tn] = __builtin_amdgcn_mfma_f32_16x16x32_bf16(al[tm], bh[tn], acc[tm][tn], 0, 0, 0);
                acc[tm][tn] = __builtin_amdgcn_mfma_f32_16x16x32_bf16(ah[tm], bh[tn], acc[tm][tn], 0, 0, 0);
            }
    }
}

// K4: h = relu(px @ W1 + b1), written directly as split bf16 (GEMM2 operand).
__global__ __launch_bounds__(256) void gemm1_fused(const ushort* __restrict__ Ah,
                                                   const ushort* __restrict__ Al,
                                                   const ushort* __restrict__ Bh,
                                                   const ushort* __restrict__ Bl,
                                                   const float* __restrict__ b1,
                                                   ushort* __restrict__ h_hi,
                                                   ushort* __restrict__ h_lo) {
    const int tid = threadIdx.x;
    const int lane = tid & 63, wave = tid >> 6;
    const int wm = wave >> 1, wn = wave & 1;
    const int l16 = lane & 15, quad = lane >> 4;
    const int m_base = blockIdx.x * 128 + wm * 64;
    const int n_base = blockIdx.y * 64 + wn * 32;
    floatx4 acc[4][2] = {};
    gemm_core(Ah, Al, Bh, Bl, IN_DIM, m_base, n_base, l16, quad, acc);
#pragma unroll
    for (int tn = 0; tn < 2; ++tn) {
        const int col = n_base + tn * 16 + l16;
        const float bv = b1[col];
#pragma unroll
        for (int tm = 0; tm < 4; ++tm)
#pragma unroll
            for (int r = 0; r < 4; ++r) {
                const int row = m_base + tm * 16 + quad * 4 + r;
                const float v = fmaxf(acc[tm][tn][r] + bv, 0.0f);
                const ushort hi = f2bf(v);
                h_hi[(size_t)row * HID + col] = hi;
                h_lo[(size_t)row * HID + col] = f2bf(v - bf2f(hi));
            }
    }
}

// K5: g2 = h @ W2 (fp32 out; aggregation + bias + sigmoid happen in K6).
__global__ __launch_bounds__(256) void gemm2(const ushort* __restrict__ Ah,
                                             const ushort* __restrict__ Al,
                                             const ushort* __restrict__ Bh,
                                             const ushort* __restrict__ Bl,
                                             float* __restrict__ C) {
    const int tid = threadIdx.x;
    const int lane = tid & 63, wave = tid >> 6;
    const int wm = wave >> 1, wn = wave & 1;
    const int l16 = lane & 15, quad = lane >> 4;
    const int m_base = blockIdx.x * 128 + wm * 64;
    const int n_base = blockIdx.y * 64 + wn * 32;
    floatx4 acc[4][2] = {};
    gemm_core(Ah, Al, Bh, Bl, HID, m_base, n_base, l16, quad, acc);
#pragma unroll
    for (int tm = 0; tm < 4; ++tm)
#pragma unroll
        for (int tn = 0; tn < 2; ++tn)
#pragma unroll
            for (int r = 0; r < 4; ++r)
                C[(size_t)(m_base + tm * 16 + quad * 4 + r) * NCLS + (n_base + tn * 16 + l16)] = acc[tm][tn][r];
}

// K6: layer-2 aggregation + bias + skip + scaled sigmoid -> fp32 out.
__global__ __launch_bounds__(256) void agg_out(const float* __restrict__ g2,
                                               const int* __restrict__ col_idx,
                                               const int* __restrict__ col_cnt,
                                               const float* __restrict__ b2,
                                               const float* __restrict__ x,
                                               const float* __restrict__ sp_p,
                                               float* __restrict__ out) {
    const int j = blockIdx.x;
    const int d = threadIdx.x;
    const int cntj = min(col_cnt[j], CAP);
    const float dj = rsqrtf((float)col_cnt[j] + 1.0f);
    float acc = dj * g2[(size_t)j * NCLS + d];
    const int* __restrict__ lst = col_idx + (size_t)j * CAP;
    int e = 0;
    for (; e + 3 < cntj; e += 4) {
        const int i0 = lst[e], i1 = lst[e + 1], i2 = lst[e + 2], i3 = lst[e + 3];
        const float d0 = rsqrtf((float)col_cnt[i0] + 1.0f);
        const float d1 = rsqrtf((float)col_cnt[i1] + 1.0f);
        const float d2 = rsqrtf((float)col_cnt[i2] + 1.0f);
        const float d3 = rsqrtf((float)col_cnt[i3] + 1.0f);
        const float v0 = g2[(size_t)i0 * NCLS + d];
        const float v1 = g2[(size_t)i1 * NCLS + d];
        const float v2 = g2[(size_t)i2 * NCLS + d];
        const float v3 = g2[(size_t)i3 * NCLS + d];
        acc += d0 * v0 + d1 * v1 + d2 * v2 + d3 * v3;
    }
    for (; e < cntj; ++e) {
        const int i = lst[e];
        acc += rsqrtf((float)col_cnt[i] + 1.0f) * g2[(size_t)i * NCLS + d];
    }
    const float sp = sp_p[0];
    const float val = dj * acc + b2[d] + x[(size_t)j * NCLS + d];
    out[(size_t)j * NCLS + d] = 1.0f / (1.0f + __expf(-sp * val));
}

extern "C" void kernel_launch(void* const* d_in, const int* in_sizes, int n_in,
                              void* d_out, int out_size, void* d_ws, size_t ws_size,
                              hipStream_t stream) {
    const float* A  = (const float*)d_in[0];   // [8192,8192] fp32 (0.0/1.0)
    const float* x  = (const float*)d_in[1];   // [8192,256]  fp32
    const float* W1 = (const float*)d_in[2];   // [256,512]   fp32
    const float* b1 = (const float*)d_in[3];   // [512]       fp32
    const float* W2 = (const float*)d_in[4];   // [512,256]   fp32
    const float* b2 = (const float*)d_in[5];   // [256]       fp32
    const float* sp = (const float*)d_in[6];   // [1]         fp32
    float* out = (float*)d_out;                // [8192,256]  fp32

    char* ws = (char*)d_ws;
    size_t off = 0;
    auto alloc = [&](size_t bytes) {
        void* p = ws + off;
        off = (off + bytes + 255) & ~(size_t)255;
        return p;
    };
    int*    col_cnt = (int*)   alloc((size_t)N_NODES * 4);
    int*    col_idx = (int*)   alloc((size_t)N_NODES * CAP * 4);     // 4 MB
    ushort* px_hi   = (ushort*)alloc((size_t)N_NODES * IN_DIM * 2);  // 4 MB
    ushort* px_lo   = (ushort*)alloc((size_t)N_NODES * IN_DIM * 2);  // 4 MB
    ushort* W1Th    = (ushort*)alloc((size_t)HID * IN_DIM * 2);
    ushort* W1Tl    = (ushort*)alloc((size_t)HID * IN_DIM * 2);
    ushort* W2Th    = (ushort*)alloc((size_t)NCLS * HID * 2);
    ushort* W2Tl    = (ushort*)alloc((size_t)NCLS * HID * 2);
    ushort* h_hi    = (ushort*)alloc((size_t)N_NODES * HID * 2);     // 8 MB
    ushort* h_lo    = (ushort*)alloc((size_t)N_NODES * HID * 2);     // 8 MB
    float*  g2      = (float*) alloc((size_t)N_NODES * NCLS * 4);    // 8 MB

    hipMemsetAsync(col_cnt, 0, (size_t)N_NODES * 4, stream);

    build_csc<<<dim3(8, 256), 256, 0, stream>>>(A, col_cnt, col_idx);
    prep_w<<<(IN_DIM * HID) / 256, 256, 0, stream>>>(W1, W2, W1Th, W1Tl, W2Th, W2Tl);

    // Layer 1: aggregate x (256-wide) first, then GEMM with fused relu+split.
    agg_x<<<N_NODES, 256, 0, stream>>>(x, col_idx, col_cnt, px_hi, px_lo);
    gemm1_fused<<<dim3(N_NODES / 128, HID / 64), 256, 0, stream>>>(
        px_hi, px_lo, W1Th, W1Tl, b1, h_hi, h_lo);

    // Layer 2: GEMM first (output 256-wide < 512-wide input), then aggregate.
    gemm2<<<dim3(N_NODES / 128, NCLS / 64), 256, 0, stream>>>(
        h_hi, h_lo, W2Th, W2Tl, g2);
    agg_out<<<N_NODES, 256, 0, stream>>>(g2, col_idx, col_cnt, b2, x, sp, out);
}

// Round 4
// 496.321 us; speedup vs baseline: 1.1856x; 1.0122x over previous
//
#include <hip/hip_runtime.h>
#include <hip/hip_bf16.h>

#define N_NODES 8192
#define IN_DIM  256
#define HID     512
#define NCLS    256
#define CAP     128   // max in-degree capacity (Poisson mean 32; 128 is safe)

typedef __attribute__((ext_vector_type(8))) __bf16 bf16x8;
typedef __attribute__((ext_vector_type(4))) float  floatx4;

static __device__ __forceinline__ float bf2f(ushort u) {
    union { float f; unsigned int i; } v; v.i = ((unsigned int)u) << 16; return v.f;
}
static __device__ __forceinline__ ushort f2bf(float f) {
    __hip_bfloat16 b = __float2bfloat16(f);   // round-to-nearest
    return *reinterpret_cast<ushort*>(&b);
}

// ---------------------------------------------------------------------------
// K1: scan A (fp32 binary, row-major [i][j]) -> per-column neighbor lists.
// Coalesced float4 loads, 4 cols/thread. Grid (8, 256): 2048 blocks, 32 rows
// each. List order nondeterministic (atomic append) but sums are order-free.
// ---------------------------------------------------------------------------
__global__ __launch_bounds__(256) void build_csc(const float* __restrict__ A,
                                                 int* __restrict__ col_cnt,
                                                 int* __restrict__ col_idx) {
    const int jbase = (blockIdx.x * 256 + threadIdx.x) * 4;
    const int i0 = blockIdx.y * 32;
    for (int ii = 0; ii < 32; ++ii) {
        const int i = i0 + ii;
        float4 v = *reinterpret_cast<const float4*>(A + (size_t)i * N_NODES + jbase);
        if (v.x != 0.0f) { int p = atomicAdd(&col_cnt[jbase + 0], 1); if (p < CAP) col_idx[(size_t)(jbase + 0) * CAP + p] = i; }
        if (v.y != 0.0f) { int p = atomicAdd(&col_cnt[jbase + 1], 1); if (p < CAP) col_idx[(size_t)(jbase + 1) * CAP + p] = i; }
        if (v.z != 0.0f) { int p = atomicAdd(&col_cnt[jbase + 2], 1); if (p < CAP) col_idx[(size_t)(jbase + 2) * CAP + p] = i; }
        if (v.w != 0.0f) { int p = atomicAdd(&col_cnt[jbase + 3], 1); if (p < CAP) col_idx[(size_t)(jbase + 3) * CAP + p] = i; }
    }
}

// K2: dis[j] = rsqrt(deg_j), deg = colsum(A) + 1 (self loop).
__global__ __launch_bounds__(256) void compute_dis(const int* __restrict__ col_cnt,
                                                   float* __restrict__ dis) {
    const int j = blockIdx.x * 256 + threadIdx.x;
    dis[j] = rsqrtf((float)col_cnt[j] + 1.0f);
}

// K3: per-edge weights w[j][e] = dis[idx[j][e]] (kills per-edge dis gather
// + rsqrt in the hot agg loops; makes the inner loop pure s_load + row-read).
__global__ __launch_bounds__(128) void fill_w(const int* __restrict__ col_idx,
                                              const int* __restrict__ col_cnt,
                                              const float* __restrict__ dis,
                                              float* __restrict__ w) {
    const int j = blockIdx.x, e = threadIdx.x;
    if (e < min(col_cnt[j], CAP))
        w[(size_t)j * CAP + e] = dis[col_idx[(size_t)j * CAP + e]];
}

// K4: transpose + split weights into bf16 hi/lo residual pairs.
__global__ __launch_bounds__(256) void prep_w(const float* __restrict__ W1,
                                              const float* __restrict__ W2,
                                              ushort* __restrict__ W1Th, ushort* __restrict__ W1Tl,
                                              ushort* __restrict__ W2Th, ushort* __restrict__ W2Tl) {
    const int idx = blockIdx.x * 256 + threadIdx.x;   // < 131072
    {
        const int k = idx / HID, n = idx % HID;
        const float v = W1[idx]; const ushort h = f2bf(v);
        W1Th[(size_t)n * IN_DIM + k] = h;
        W1Tl[(size_t)n * IN_DIM + k] = f2bf(v - bf2f(h));
    }
    {
        const int k = idx / NCLS, n = idx % NCLS;
        const float v = W2[idx]; const ushort h = f2bf(v);
        W2Th[(size_t)n * HID + k] = h;
        W2Tl[(size_t)n * HID + k] = f2bf(v - bf2f(h));
    }
}

// ---------------------------------------------------------------------------
// K5: layer-1 aggregation (P commutes with the feature GEMM; aggregate the
// 256-wide x, not the 512-wide hidden). Wave-per-node: 64 lanes x float4 =
// one 1 KB row per vector load. Node index forced wave-uniform so idx/weight
// loads scalarize to s_load_dwordx4. 4-deep unroll = 4 dwordx4 in flight.
// px[j] = dis_j*(sum w_e * x[idx_e] + dis_j*x[j]) -> split bf16.
// ---------------------------------------------------------------------------
__global__ __launch_bounds__(256) void agg_x(const float* __restrict__ x,
                                             const int* __restrict__ col_idx,
                                             const int* __restrict__ col_cnt,
                                             const float* __restrict__ dis,
                                             const float* __restrict__ w,
                                             ushort* __restrict__ px_hi,
                                             ushort* __restrict__ px_lo) {
    const int j = __builtin_amdgcn_readfirstlane(blockIdx.x * 4 + (threadIdx.x >> 6));
    const int d = (threadIdx.x & 63) * 4;
    const int cnt = min(col_cnt[j], CAP);
    const float dj = dis[j];
    const float4 self = *reinterpret_cast<const float4*>(x + (size_t)j * IN_DIM + d);
    float ax = dj * self.x, ay = dj * self.y, az = dj * self.z, aw = dj * self.w;
    const int*   __restrict__ lst = col_idx + (size_t)j * CAP;
    const float* __restrict__ wl  = w       + (size_t)j * CAP;
    int e = 0;
    for (; e + 4 <= cnt; e += 4) {
        const int i0 = lst[e], i1 = lst[e + 1], i2 = lst[e + 2], i3 = lst[e + 3];
        const float w0 = wl[e], w1 = wl[e + 1], w2 = wl[e + 2], w3 = wl[e + 3];
        const float4 v0 = *reinterpret_cast<const float4*>(x + (size_t)i0 * IN_DIM + d);
        const float4 v1 = *reinterpret_cast<const float4*>(x + (size_t)i1 * IN_DIM + d);
        const float4 v2 = *reinterpret_cast<const float4*>(x + (size_t)i2 * IN_DIM + d);
        const float4 v3 = *reinterpret_cast<const float4*>(x + (size_t)i3 * IN_DIM + d);
        ax += w0 * v0.x + w1 * v1.x + w2 * v2.x + w3 * v3.x;
        ay += w0 * v0.y + w1 * v1.y + w2 * v2.y + w3 * v3.y;
        az += w0 * v0.z + w1 * v1.z + w2 * v2.z + w3 * v3.z;
        aw += w0 * v0.w + w1 * v1.w + w2 * v2.w + w3 * v3.w;
    }
    for (; e < cnt; ++e) {
        const int i = lst[e];
        const float we = wl[e];
        const float4 v = *reinterpret_cast<const float4*>(x + (size_t)i * IN_DIM + d);
        ax += we * v.x; ay += we * v.y; az += we * v.z; aw += we * v.w;
    }
    ax *= dj; ay *= dj; az *= dj; aw *= dj;
    const ushort hx = f2bf(ax), hy = f2bf(ay), hz = f2bf(az), hw = f2bf(aw);
    *reinterpret_cast<ushort4*>(px_hi + (size_t)j * IN_DIM + d) = ushort4{hx, hy, hz, hw};
    *reinterpret_cast<ushort4*>(px_lo + (size_t)j * IN_DIM + d) =
        ushort4{f2bf(ax - bf2f(hx)), f2bf(ay - bf2f(hy)), f2bf(az - bf2f(hz)), f2bf(aw - bf2f(hw))};
}

// ---------------------------------------------------------------------------
// Shared GEMM core: acc[4][2] += (Ah+Al)[M,K] @ (Bh+Bl)[N,K]^T, split-bf16
// 3-product (Ah@Bh + Ah@Bl + Al@Bh; Al@Bl ~2^-18 dropped). 16x16x32 MFMA.
// Block = 4 waves (2 M x 2 N), wave tile 64x32, block tile 128x64.
// ---------------------------------------------------------------------------
__device__ __forceinline__ void gemm_core(const ushort* __restrict__ Ah,
                                          const ushort* __restrict__ Al,
                                          const ushort* __restrict__ Bh,
                                          const ushort* __restrict__ Bl,
                                          int K, int m_base, int n_base,
                                          int l16, int quad, floatx4 acc[4][2]) {
    for (int k0 = 0; k0 < K; k0 += 32) {
        const int kf = k0 + quad * 8;
        bf16x8 ah[4], al[4], bh[2], bl[2];
#pragma unroll
        for (int t = 0; t < 4; ++t) {
            const size_t ao = (size_t)(m_base + t * 16 + l16) * K + kf;
            ah[t] = *reinterpret_cast<const bf16x8*>(Ah + ao);
            al[t] = *reinterpret_cast<const bf16x8*>(Al + ao);
        }
#pragma unroll
        for (int t = 0; t < 2; ++t) {
            const size_t bo = (size_t)(n_base + t * 16 + l16) * K + kf;
            bh[t] = *reinterpret_cast<const bf16x8*>(Bh + bo);
            bl[t] = *reinterpret_cast<const bf16x8*>(Bl + bo);
        }
#pragma unroll
        for (int tm = 0; tm < 4; ++tm)
#pragma unroll
            for (int tn = 0; tn < 2; ++tn) {
                acc[tm][tn] = __builtin_amdgcn_mfma_f32_16x16x32_bf16(ah[tm], bl[tn], acc[tm][tn], 0, 0, 0);
                acc[tm][tn] = __builtin_amdgcn_mfma_f32_16x16x32_bf16(al[tm], bh[tn], acc[tm][tn], 0, 0, 0);
                acc[tm][tn] = __builtin_amdgcn_mfma_f32_16x16x32_bf16(ah[tm], bh[tn], acc[tm][tn], 0, 0, 0);
            }
    }
}

// K6: h = relu(px @ W1 + b1), written directly as split bf16 (GEMM2 operand).
__global__ __launch_bounds__(256) void gemm1_fused(const ushort* __restrict__ Ah,
                                                   const ushort* __restrict__ Al,
                                                   const ushort* __restrict__ Bh,
                                                   const ushort* __restrict__ Bl,
                                                   const float* __restrict__ b1,
                                                   ushort* __restrict__ h_hi,
                                                   ushort* __restrict__ h_lo) {
    const int tid = threadIdx.x;
    const int lane = tid & 63, wave = tid >> 6;
    const int wm = wave >> 1, wn = wave & 1;
    const int l16 = lane & 15, quad = lane >> 4;
    const int m_base = blockIdx.x * 128 + wm * 64;
    const int n_base = blockIdx.y * 64 + wn * 32;
    floatx4 acc[4][2] = {};
    gemm_core(Ah, Al, Bh, Bl, IN_DIM, m_base, n_base, l16, quad, acc);
#pragma unroll
    for (int tn = 0; tn < 2; ++tn) {
        const int col = n_base + tn * 16 + l16;
        const float bv = b1[col];
#pragma unroll
        for (int tm = 0; tm < 4; ++tm)
#pragma unroll
            for (int r = 0; r < 4; ++r) {
                const int row = m_base + tm * 16 + quad * 4 + r;
                const float v = fmaxf(acc[tm][tn][r] + bv, 0.0f);
                const ushort hi = f2bf(v);
                h_hi[(size_t)row * HID + col] = hi;
                h_lo[(size_t)row * HID + col] = f2bf(v - bf2f(hi));
            }
    }
}

// K7: g2 = h @ W2 (fp32; aggregation + bias + sigmoid in K8).
__global__ __launch_bounds__(256) void gemm2(const ushort* __restrict__ Ah,
                                             const ushort* __restrict__ Al,
                                             const ushort* __restrict__ Bh,
                                             const ushort* __restrict__ Bl,
                                             float* __restrict__ C) {
    const int tid = threadIdx.x;
    const int lane = tid & 63, wave = tid >> 6;
    const int wm = wave >> 1, wn = wave & 1;
    const int l16 = lane & 15, quad = lane >> 4;
    const int m_base = blockIdx.x * 128 + wm * 64;
    const int n_base = blockIdx.y * 64 + wn * 32;
    floatx4 acc[4][2] = {};
    gemm_core(Ah, Al, Bh, Bl, HID, m_base, n_base, l16, quad, acc);
#pragma unroll
    for (int tm = 0; tm < 4; ++tm)
#pragma unroll
        for (int tn = 0; tn < 2; ++tn)
#pragma unroll
            for (int r = 0; r < 4; ++r)
                C[(size_t)(m_base + tm * 16 + quad * 4 + r) * NCLS + (n_base + tn * 16 + l16)] = acc[tm][tn][r];
}

// ---------------------------------------------------------------------------
// K8: layer-2 aggregation + bias + skip + scaled sigmoid. Same wave-per-node
// float4 gather structure as K5.
// ---------------------------------------------------------------------------
__global__ __launch_bounds__(256) void agg_out(const float* __restrict__ g2,
                                               const int* __restrict__ col_idx,
                                               const int* __restrict__ col_cnt,
                                               const float* __restrict__ dis,
                                               const float* __restrict__ w,
                                               const float* __restrict__ b2,
                                               const float* __restrict__ x,
                                               const float* __restrict__ sp_p,
                                               float* __restrict__ out) {
    const int j = __builtin_amdgcn_readfirstlane(blockIdx.x * 4 + (threadIdx.x >> 6));
    const int d = (threadIdx.x & 63) * 4;
    const int cnt = min(col_cnt[j], CAP);
    const float dj = dis[j];
    const float4 self = *reinterpret_cast<const float4*>(g2 + (size_t)j * NCLS + d);
    float ax = dj * self.x, ay = dj * self.y, az = dj * self.z, aw = dj * self.w;
    const int*   __restrict__ lst = col_idx + (size_t)j * CAP;
    const float* __restrict__ wl  = w       + (size_t)j * CAP;
    int e = 0;
    for (; e + 4 <= cnt; e += 4) {
        const int i0 = lst[e], i1 = lst[e + 1], i2 = lst[e + 2], i3 = lst[e + 3];
        const float w0 = wl[e], w1 = wl[e + 1], w2 = wl[e + 2], w3 = wl[e + 3];
        const float4 v0 = *reinterpret_cast<const float4*>(g2 + (size_t)i0 * NCLS + d);
        const float4 v1 = *reinterpret_cast<const float4*>(g2 + (size_t)i1 * NCLS + d);
        const float4 v2 = *reinterpret_cast<const float4*>(g2 + (size_t)i2 * NCLS + d);
        const float4 v3 = *reinterpret_cast<const float4*>(g2 + (size_t)i3 * NCLS + d);
        ax += w0 * v0.x + w1 * v1.x + w2 * v2.x + w3 * v3.x;
        ay += w0 * v0.y + w1 * v1.y + w2 * v2.y + w3 * v3.y;
        az += w0 * v0.z + w1 * v1.z + w2 * v2.z + w3 * v3.z;
        aw += w0 * v0.w + w1 * v1.w + w2 * v2.w + w3 * v3.w;
    }
    for (; e < cnt; ++e) {
        const int i = lst[e];
        const float we = wl[e];
        const float4 v = *reinterpret_cast<const float4*>(g2 + (size_t)i * NCLS + d);
        ax += we * v.x; ay += we * v.y; az += we * v.z; aw += we * v.w;
    }
    const float sp = sp_p[0];
    const float4 bv = *reinterpret_cast<const float4*>(b2 + d);
    const float4 xv = *reinterpret_cast<const float4*>(x + (size_t)j * NCLS + d);
    float4 o;
    o.x = 1.0f / (1.0f + __expf(-sp * (dj * ax + bv.x + xv.x)));
    o.y = 1.0f / (1.0f + __expf(-sp * (dj * ay + bv.y + xv.y)));
    o.z = 1.0f / (1.0f + __expf(-sp * (dj * az + bv.z + xv.z)));
    o.w = 1.0f / (1.0f + __expf(-sp * (dj * aw + bv.w + xv.w)));
    *reinterpret_cast<float4*>(out + (size_t)j * NCLS + d) = o;
}

extern "C" void kernel_launch(void* const* d_in, const int* in_sizes, int n_in,
                              void* d_out, int out_size, void* d_ws, size_t ws_size,
                              hipStream_t stream) {
    const float* A  = (const float*)d_in[0];   // [8192,8192] fp32 (0.0/1.0)
    const float* x  = (const float*)d_in[1];   // [8192,256]  fp32
    const float* W1 = (const float*)d_in[2];   // [256,512]   fp32
    const float* b1 = (const float*)d_in[3];   // [512]       fp32
    const float* W2 = (const float*)d_in[4];   // [512,256]   fp32
    const float* b2 = (const float*)d_in[5];   // [256]       fp32
    const float* sp = (const float*)d_in[6];   // [1]         fp32
    float* out = (float*)d_out;                // [8192,256]  fp32

    char* ws = (char*)d_ws;
    size_t off = 0;
    auto alloc = [&](size_t bytes) {
        void* p = ws + off;
        off = (off + bytes + 255) & ~(size_t)255;
        return p;
    };
    int*    col_cnt = (int*)   alloc((size_t)N_NODES * 4);
    float*  dis     = (float*) alloc((size_t)N_NODES * 4);
    int*    col_idx = (int*)   alloc((size_t)N_NODES * CAP * 4);     // 4 MB
    float*  wedge   = (float*) alloc((size_t)N_NODES * CAP * 4);     // 4 MB
    ushort* px_hi   = (ushort*)alloc((size_t)N_NODES * IN_DIM * 2);  // 4 MB
    ushort* px_lo   = (ushort*)alloc((size_t)N_NODES * IN_DIM * 2);  // 4 MB
    ushort* W1Th    = (ushort*)alloc((size_t)HID * IN_DIM * 2);
    ushort* W1Tl    = (ushort*)alloc((size_t)HID * IN_DIM * 2);
    ushort* W2Th    = (ushort*)alloc((size_t)NCLS * HID * 2);
    ushort* W2Tl    = (ushort*)alloc((size_t)NCLS * HID * 2);
    ushort* h_hi    = (ushort*)alloc((size_t)N_NODES * HID * 2);     // 8 MB
    ushort* h_lo    = (ushort*)alloc((size_t)N_NODES * HID * 2);     // 8 MB
    float*  g2      = (float*) alloc((size_t)N_NODES * NCLS * 4);    // 8 MB

    hipMemsetAsync(col_cnt, 0, (size_t)N_NODES * 4, stream);

    build_csc<<<dim3(8, 256), 256, 0, stream>>>(A, col_cnt, col_idx);
    compute_dis<<<N_NODES / 256, 256, 0, stream>>>(col_cnt, dis);
    fill_w<<<N_NODES, 128, 0, stream>>>(col_idx, col_cnt, dis, wedge);
    prep_w<<<(IN_DIM * HID) / 256, 256, 0, stream>>>(W1, W2, W1Th, W1Tl, W2Th, W2Tl);

    // Layer 1: aggregate x (256-wide) first, then GEMM with fused relu+split.
    agg_x<<<N_NODES / 4, 256, 0, stream>>>(x, col_idx, col_cnt, dis, wedge, px_hi, px_lo);
    gemm1_fused<<<dim3(N_NODES / 128, HID / 64), 256, 0, stream>>>(
        px_hi, px_lo, W1Th, W1Tl, b1, h_hi, h_lo);

    // Layer 2: GEMM first (output 256-wide < 512-wide input), then aggregate.
    gemm2<<<dim3(N_NODES / 128, NCLS / 64), 256, 0, stream>>>(
        h_hi, h_lo, W2Th, W2Tl, g2);
    agg_out<<<N_NODES / 4, 256, 0, stream>>>(g2, col_idx, col_cnt, dis, wedge, b2, x, sp, out);
}

// Round 5
// 474.645 us; speedup vs baseline: 1.2398x; 1.0457x over previous
//
#include <hip/hip_runtime.h>
#include <hip/hip_bf16.h>

#define N_NODES 8192
#define IN_DIM  256
#define HID     512
#define NCLS    256
#define CAP     128   // max in-degree capacity (Poisson mean 32; max over 8192 draws ~56)

typedef __attribute__((ext_vector_type(8))) __bf16 bf16x8;
typedef __attribute__((ext_vector_type(4))) float  floatx4;

static __device__ __forceinline__ float bf2f(ushort u) {
    union { float f; unsigned int i; } v; v.i = ((unsigned int)u) << 16; return v.f;
}
static __device__ __forceinline__ ushort f2bf(float f) {
    __hip_bfloat16 b = __float2bfloat16(f);   // round-to-nearest
    return *reinterpret_cast<ushort*>(&b);
}
// unpack one uint holding two packed bf16 (little-endian: lo ushort = element d)
static __device__ __forceinline__ void bfpair(unsigned int u, float& lo, float& hi) {
    union { float f; unsigned int i; } a, b;
    a.i = u << 16; b.i = u & 0xFFFF0000u;
    lo = a.f; hi = b.f;
}

// ---------------------------------------------------------------------------
// K1: scan A (fp32 binary, row-major [i][j]) -> per-column neighbor lists.
// Coalesced float4 loads, 4 cols/thread. ~0.5 expected nonzeros per thread,
// so atomics are rare. HBM-bound: 256 MB ~ 41 us floor.
// ---------------------------------------------------------------------------
__global__ __launch_bounds__(256) void build_csc(const float* __restrict__ A,
                                                 int* __restrict__ col_cnt,
                                                 int* __restrict__ col_idx) {
    const int jbase = (blockIdx.x * 256 + threadIdx.x) * 4;
    const int i0 = blockIdx.y * 32;
    for (int ii = 0; ii < 32; ++ii) {
        const int i = i0 + ii;
        float4 v = *reinterpret_cast<const float4*>(A + (size_t)i * N_NODES + jbase);
        if (v.x != 0.0f) { int p = atomicAdd(&col_cnt[jbase + 0], 1); if (p < CAP) col_idx[(size_t)(jbase + 0) * CAP + p] = i; }
        if (v.y != 0.0f) { int p = atomicAdd(&col_cnt[jbase + 1], 1); if (p < CAP) col_idx[(size_t)(jbase + 1) * CAP + p] = i; }
        if (v.z != 0.0f) { int p = atomicAdd(&col_cnt[jbase + 2], 1); if (p < CAP) col_idx[(size_t)(jbase + 2) * CAP + p] = i; }
        if (v.w != 0.0f) { int p = atomicAdd(&col_cnt[jbase + 3], 1); if (p < CAP) col_idx[(size_t)(jbase + 3) * CAP + p] = i; }
    }
}

// K2: per-edge weights w[j][e] = rsqrt(deg[idx]+1), dis folded inline.
__global__ __launch_bounds__(128) void fill_w(const int* __restrict__ col_idx,
                                              const int* __restrict__ col_cnt,
                                              float* __restrict__ w) {
    const int j = blockIdx.x, e = threadIdx.x;
    if (e < min(col_cnt[j], CAP))
        w[(size_t)j * CAP + e] = rsqrtf((float)col_cnt[col_idx[(size_t)j * CAP + e]] + 1.0f);
}

// K3: bf16 copy of x (4 MB -> fits one XCD's L2; halves gather traffic).
__global__ __launch_bounds__(256) void cvt_x(const float* __restrict__ x,
                                             ushort* __restrict__ xb) {
    const int i = (blockIdx.x * 256 + threadIdx.x) * 4;
    const float4 v = *reinterpret_cast<const float4*>(x + i);
    *reinterpret_cast<ushort4*>(xb + i) = ushort4{f2bf(v.x), f2bf(v.y), f2bf(v.z), f2bf(v.w)};
}

// K4: transpose + split weights into bf16 hi/lo residual pairs.
__global__ __launch_bounds__(256) void prep_w(const float* __restrict__ W1,
                                              const float* __restrict__ W2,
                                              ushort* __restrict__ W1Th, ushort* __restrict__ W1Tl,
                                              ushort* __restrict__ W2Th, ushort* __restrict__ W2Tl) {
    const int idx = blockIdx.x * 256 + threadIdx.x;   // < 131072
    {
        const int k = idx / HID, n = idx % HID;
        const float v = W1[idx]; const ushort h = f2bf(v);
        W1Th[(size_t)n * IN_DIM + k] = h;
        W1Tl[(size_t)n * IN_DIM + k] = f2bf(v - bf2f(h));
    }
    {
        const int k = idx / NCLS, n = idx % NCLS;
        const float v = W2[idx]; const ushort h = f2bf(v);
        W2Th[(size_t)n * HID + k] = h;
        W2Tl[(size_t)n * HID + k] = f2bf(v - bf2f(h));
    }
}

// ---------------------------------------------------------------------------
// K5: layer-1 aggregation over bf16 x rows. Wave-per-node, lane owns 4 feats
// (uint2 = 4 bf16 = 8 B; 64 lanes x 8 B = one 512 B row per load instr).
// 8-deep edge unroll = 4 KB in flight per wave. Node index wave-uniform so
// idx/w loads scalarize. px -> split bf16 (GEMM1 A-operand).
// ---------------------------------------------------------------------------
__global__ __launch_bounds__(256) void agg_x(const ushort* __restrict__ xb,
                                             const int* __restrict__ col_idx,
                                             const int* __restrict__ col_cnt,
                                             const float* __restrict__ w,
                                             ushort* __restrict__ px_hi,
                                             ushort* __restrict__ px_lo) {
    const int j = __builtin_amdgcn_readfirstlane(blockIdx.x * 4 + (threadIdx.x >> 6));
    const int d = (threadIdx.x & 63) * 4;
    const int cntr = col_cnt[j];
    const int cnt = min(cntr, CAP);
    const float dj = rsqrtf((float)cntr + 1.0f);
    float a0, a1, a2, a3;
    {
        const uint2 sv = *reinterpret_cast<const uint2*>(xb + (size_t)j * IN_DIM + d);
        float f0, f1, f2, f3;
        bfpair(sv.x, f0, f1); bfpair(sv.y, f2, f3);
        a0 = dj * f0; a1 = dj * f1; a2 = dj * f2; a3 = dj * f3;
    }
    const int*   __restrict__ lst = col_idx + (size_t)j * CAP;
    const float* __restrict__ wl  = w       + (size_t)j * CAP;
    int e = 0;
    for (; e + 8 <= cnt; e += 8) {
        uint2 rv[8]; float we[8];
#pragma unroll
        for (int q = 0; q < 8; ++q) {
            rv[q] = *reinterpret_cast<const uint2*>(xb + (size_t)lst[e + q] * IN_DIM + d);
            we[q] = wl[e + q];
        }
#pragma unroll
        for (int q = 0; q < 8; ++q) {
            float f0, f1, f2, f3;
            bfpair(rv[q].x, f0, f1); bfpair(rv[q].y, f2, f3);
            a0 += we[q] * f0; a1 += we[q] * f1; a2 += we[q] * f2; a3 += we[q] * f3;
        }
    }
    for (; e < cnt; ++e) {
        const uint2 rv = *reinterpret_cast<const uint2*>(xb + (size_t)lst[e] * IN_DIM + d);
        const float we = wl[e];
        float f0, f1, f2, f3;
        bfpair(rv.x, f0, f1); bfpair(rv.y, f2, f3);
        a0 += we * f0; a1 += we * f1; a2 += we * f2; a3 += we * f3;
    }
    a0 *= dj; a1 *= dj; a2 *= dj; a3 *= dj;
    const ushort h0 = f2bf(a0), h1 = f2bf(a1), h2 = f2bf(a2), h3 = f2bf(a3);
    *reinterpret_cast<ushort4*>(px_hi + (size_t)j * IN_DIM + d) = ushort4{h0, h1, h2, h3};
    *reinterpret_cast<ushort4*>(px_lo + (size_t)j * IN_DIM + d) =
        ushort4{f2bf(a0 - bf2f(h0)), f2bf(a1 - bf2f(h1)), f2bf(a2 - bf2f(h2)), f2bf(a3 - bf2f(h3))};
}

// ---------------------------------------------------------------------------
// Shared GEMM core: acc[4][2] += (Ah+Al)[M,K] @ (Bh+Bl)[N,K]^T, split-bf16
// 3-product. 16x16x32 MFMA. Block = 4 waves (2Mx2N), block tile 128x64.
// ---------------------------------------------------------------------------
__device__ __forceinline__ void gemm_core(const ushort* __restrict__ Ah,
                                          const ushort* __restrict__ Al,
                                          const ushort* __restrict__ Bh,
                                          const ushort* __restrict__ Bl,
                                          int K, int m_base, int n_base,
                                          int l16, int quad, floatx4 acc[4][2]) {
    for (int k0 = 0; k0 < K; k0 += 32) {
        const int kf = k0 + quad * 8;
        bf16x8 ah[4], al[4], bh[2], bl[2];
#pragma unroll
        for (int t = 0; t < 4; ++t) {
            const size_t ao = (size_t)(m_base + t * 16 + l16) * K + kf;
            ah[t] = *reinterpret_cast<const bf16x8*>(Ah + ao);
            al[t] = *reinterpret_cast<const bf16x8*>(Al + ao);
        }
#pragma unroll
        for (int t = 0; t < 2; ++t) {
            const size_t bo = (size_t)(n_base + t * 16 + l16) * K + kf;
            bh[t] = *reinterpret_cast<const bf16x8*>(Bh + bo);
            bl[t] = *reinterpret_cast<const bf16x8*>(Bl + bo);
        }
#pragma unroll
        for (int tm = 0; tm < 4; ++tm)
#pragma unroll
            for (int tn = 0; tn < 2; ++tn) {
                acc[tm][tn] = __builtin_amdgcn_mfma_f32_16x16x32_bf16(ah[tm], bl[tn], acc[tm][tn], 0, 0, 0);
                acc[tm][tn] = __builtin_amdgcn_mfma_f32_16x16x32_bf16(al[tm], bh[tn], acc[tm][tn], 0, 0, 0);
                acc[tm][tn] = __builtin_amdgcn_mfma_f32_16x16x32_bf16(ah[tm], bh[tn], acc[tm][tn], 0, 0, 0);
            }
    }
}

// K6: h = relu(px @ W1 + b1) -> split bf16 (GEMM2 operand).
__global__ __launch_bounds__(256) void gemm1_fused(const ushort* __restrict__ Ah,
                                                   const ushort* __restrict__ Al,
                                                   const ushort* __restrict__ Bh,
                                                   const ushort* __restrict__ Bl,
                                                   const float* __restrict__ b1,
                                                   ushort* __restrict__ h_hi,
                                                   ushort* __restrict__ h_lo) {
    const int tid = threadIdx.x;
    const int lane = tid & 63, wave = tid >> 6;
    const int wm = wave >> 1, wn = wave & 1;
    const int l16 = lane & 15, quad = lane >> 4;
    const int m_base = blockIdx.x * 128 + wm * 64;
    const int n_base = blockIdx.y * 64 + wn * 32;
    floatx4 acc[4][2] = {};
    gemm_core(Ah, Al, Bh, Bl, IN_DIM, m_base, n_base, l16, quad, acc);
#pragma unroll
    for (int tn = 0; tn < 2; ++tn) {
        const int col = n_base + tn * 16 + l16;
        const float bv = b1[col];
#pragma unroll
        for (int tm = 0; tm < 4; ++tm)
#pragma unroll
            for (int r = 0; r < 4; ++r) {
                const int row = m_base + tm * 16 + quad * 4 + r;
                const float v = fmaxf(acc[tm][tn][r] + bv, 0.0f);
                const ushort hi = f2bf(v);
                h_hi[(size_t)row * HID + col] = hi;
                h_lo[(size_t)row * HID + col] = f2bf(v - bf2f(hi));
            }
    }
}

// K7: g2 = h @ W2, written as bf16 (4 MB -> XCD-L2-resident gather source;
// rounding adds ~3e-4 post-aggregation, negligible vs 2e-2 threshold).
__global__ __launch_bounds__(256) void gemm2(const ushort* __restrict__ Ah,
                                             const ushort* __restrict__ Al,
                                             const ushort* __restrict__ Bh,
                                             const ushort* __restrict__ Bl,
                                             ushort* __restrict__ g2b) {
    const int tid = threadIdx.x;
    const int lane = tid & 63, wave = tid >> 6;
    const int wm = wave >> 1, wn = wave & 1;
    const int l16 = lane & 15, quad = lane >> 4;
    const int m_base = blockIdx.x * 128 + wm * 64;
    const int n_base = blockIdx.y * 64 + wn * 32;
    floatx4 acc[4][2] = {};
    gemm_core(Ah, Al, Bh, Bl, HID, m_base, n_base, l16, quad, acc);
#pragma unroll
    for (int tm = 0; tm < 4; ++tm)
#pragma unroll
        for (int tn = 0; tn < 2; ++tn)
#pragma unroll
            for (int r = 0; r < 4; ++r)
                g2b[(size_t)(m_base + tm * 16 + quad * 4 + r) * NCLS + (n_base + tn * 16 + l16)] =
                    f2bf(acc[tm][tn][r]);
}

// ---------------------------------------------------------------------------
// K8: layer-2 aggregation over bf16 g2 rows + bias + skip + scaled sigmoid.
// Same wave-per-node bf16 gather structure as K5; fp32 epilogue.
// ---------------------------------------------------------------------------
__global__ __launch_bounds__(256) void agg_out(const ushort* __restrict__ g2b,
                                               const int* __restrict__ col_idx,
                                               const int* __restrict__ col_cnt,
                                               const float* __restrict__ w,
                                               const float* __restrict__ b2,
                                               const float* __restrict__ x,
                                               const float* __restrict__ sp_p,
                                               float* __restrict__ out) {
    const int j = __builtin_amdgcn_readfirstlane(blockIdx.x * 4 + (threadIdx.x >> 6));
    const int d = (threadIdx.x & 63) * 4;
    const int cntr = col_cnt[j];
    const int cnt = min(cntr, CAP);
    const float dj = rsqrtf((float)cntr + 1.0f);
    float a0, a1, a2, a3;
    {
        const uint2 sv = *reinterpret_cast<const uint2*>(g2b + (size_t)j * NCLS + d);
        float f0, f1, f2, f3;
        bfpair(sv.x, f0, f1); bfpair(sv.y, f2, f3);
        a0 = dj * f0; a1 = dj * f1; a2 = dj * f2; a3 = dj * f3;
    }
    const int*   __restrict__ lst = col_idx + (size_t)j * CAP;
    const float* __restrict__ wl  = w       + (size_t)j * CAP;
    int e = 0;
    for (; e + 8 <= cnt; e += 8) {
        uint2 rv[8]; float we[8];
#pragma unroll
        for (int q = 0; q < 8; ++q) {
            rv[q] = *reinterpret_cast<const uint2*>(g2b + (size_t)lst[e + q] * NCLS + d);
            we[q] = wl[e + q];
        }
#pragma unroll
        for (int q = 0; q < 8; ++q) {
            float f0, f1, f2, f3;
            bfpair(rv[q].x, f0, f1); bfpair(rv[q].y, f2, f3);
            a0 += we[q] * f0; a1 += we[q] * f1; a2 += we[q] * f2; a3 += we[q] * f3;
        }
    }
    for (; e < cnt; ++e) {
        const uint2 rv = *reinterpret_cast<const uint2*>(g2b + (size_t)lst[e] * NCLS + d);
        const float we = wl[e];
        float f0, f1, f2, f3;
        bfpair(rv.x, f0, f1); bfpair(rv.y, f2, f3);
        a0 += we * f0; a1 += we * f1; a2 += we * f2; a3 += we * f3;
    }
    const float sp = sp_p[0];
    const float4 bv = *reinterpret_cast<const float4*>(b2 + d);
    const float4 xv = *reinterpret_cast<const float4*>(x + (size_t)j * NCLS + d);
    float4 o;
    o.x = 1.0f / (1.0f + __expf(-sp * (dj * a0 + bv.x + xv.x)));
    o.y = 1.0f / (1.0f + __expf(-sp * (dj * a1 + bv.y + xv.y)));
    o.z = 1.0f / (1.0f + __expf(-sp * (dj * a2 + bv.z + xv.z)));
    o.w = 1.0f / (1.0f + __expf(-sp * (dj * a3 + bv.w + xv.w)));
    *reinterpret_cast<float4*>(out + (size_t)j * NCLS + d) = o;
}

extern "C" void kernel_launch(void* const* d_in, const int* in_sizes, int n_in,
                              void* d_out, int out_size, void* d_ws, size_t ws_size,
                              hipStream_t stream) {
    const float* A  = (const float*)d_in[0];   // [8192,8192] fp32 (0.0/1.0)
    const float* x  = (const float*)d_in[1];   // [8192,256]  fp32
    const float* W1 = (const float*)d_in[2];   // [256,512]   fp32
    const float* b1 = (const float*)d_in[3];   // [512]       fp32
    const float* W2 = (const float*)d_in[4];   // [512,256]   fp32
    const float* b2 = (const float*)d_in[5];   // [256]       fp32
    const float* sp = (const float*)d_in[6];   // [1]         fp32
    float* out = (float*)d_out;                // [8192,256]  fp32

    char* ws = (char*)d_ws;
    size_t off = 0;
    auto alloc = [&](size_t bytes) {
        void* p = ws + off;
        off = (off + bytes + 255) & ~(size_t)255;
        return p;
    };
    int*    col_cnt = (int*)   alloc((size_t)N_NODES * 4);
    int*    col_idx = (int*)   alloc((size_t)N_NODES * CAP * 4);     // 4 MB
    float*  wedge   = (float*) alloc((size_t)N_NODES * CAP * 4);     // 4 MB
    ushort* xb      = (ushort*)alloc((size_t)N_NODES * IN_DIM * 2);  // 4 MB
    ushort* px_hi   = (ushort*)alloc((size_t)N_NODES * IN_DIM * 2);  // 4 MB
    ushort* px_lo   = (ushort*)alloc((size_t)N_NODES * IN_DIM * 2);  // 4 MB
    ushort* W1Th    = (ushort*)alloc((size_t)HID * IN_DIM * 2);
    ushort* W1Tl    = (ushort*)alloc((size_t)HID * IN_DIM * 2);
    ushort* W2Th    = (ushort*)alloc((size_t)NCLS * HID * 2);
    ushort* W2Tl    = (ushort*)alloc((size_t)NCLS * HID * 2);
    ushort* h_hi    = (ushort*)alloc((size_t)N_NODES * HID * 2);     // 8 MB
    ushort* h_lo    = (ushort*)alloc((size_t)N_NODES * HID * 2);     // 8 MB
    ushort* g2b     = (ushort*)alloc((size_t)N_NODES * NCLS * 2);    // 4 MB

    hipMemsetAsync(col_cnt, 0, (size_t)N_NODES * 4, stream);

    build_csc<<<dim3(8, 256), 256, 0, stream>>>(A, col_cnt, col_idx);
    fill_w<<<N_NODES, 128, 0, stream>>>(col_idx, col_cnt, wedge);
    cvt_x<<<(N_NODES * IN_DIM) / 1024, 256, 0, stream>>>(x, xb);
    prep_w<<<(IN_DIM * HID) / 256, 256, 0, stream>>>(W1, W2, W1Th, W1Tl, W2Th, W2Tl);

    // Layer 1: aggregate bf16 x (L2-resident) first, then split-GEMM + relu.
    agg_x<<<N_NODES / 4, 256, 0, stream>>>(xb, col_idx, col_cnt, wedge, px_hi, px_lo);
    gemm1_fused<<<dim3(N_NODES / 128, HID / 64), 256, 0, stream>>>(
        px_hi, px_lo, W1Th, W1Tl, b1, h_hi, h_lo);

    // Layer 2: GEMM to bf16 g2, then aggregate + epilogue.
    gemm2<<<dim3(N_NODES / 128, NCLS / 64), 256, 0, stream>>>(
        h_hi, h_lo, W2Th, W2Tl, g2b);
    agg_out<<<N_NODES / 4, 256, 0, stream>>>(g2b, col_idx, col_cnt, wedge, b2, x, sp, out);
}

// Round 7
// 460.232 us; speedup vs baseline: 1.2786x; 1.0313x over previous
//
#include <hip/hip_runtime.h>
#include <hip/hip_bf16.h>

#define N_NODES 8192
#define IN_DIM  256
#define HID     512
#define NCLS    256
#define CAP     128   // max in-degree capacity (Poisson mean 32; max over 8192 draws ~56)

typedef __attribute__((ext_vector_type(8))) __bf16 bf16x8;
typedef __attribute__((ext_vector_type(4))) float  floatx4;   // native clang vector: ok for nontemporal builtins

static __device__ __forceinline__ float bf2f(ushort u) {
    union { float f; unsigned int i; } v; v.i = ((unsigned int)u) << 16; return v.f;
}
static __device__ __forceinline__ ushort f2bf(float f) {
    __hip_bfloat16 b = __float2bfloat16(f);   // round-to-nearest
    return *reinterpret_cast<ushort*>(&b);
}
// unpack one uint holding two packed bf16 (little-endian: lo ushort = element d)
static __device__ __forceinline__ void bfpair(unsigned int u, float& lo, float& hi) {
    union { float f; unsigned int i; } a, b;
    a.i = u << 16; b.i = u & 0xFFFF0000u;
    lo = a.f; hi = b.f;
}

// ---------------------------------------------------------------------------
// K1: scan A (fp32 binary, row-major [i][j]) -> per-column neighbor lists.
// Nontemporal 16B loads (A is read exactly once; keep it from evicting the
// agg gather sources out of L2/L3). ~0.5 nonzeros/thread -> atomics rare.
// HBM-bound: 256 MB ~ 41 us floor.
// ---------------------------------------------------------------------------
__global__ __launch_bounds__(256) void build_csc(const float* __restrict__ A,
                                                 int* __restrict__ col_cnt,
                                                 int* __restrict__ col_idx) {
    const int jbase = (blockIdx.x * 256 + threadIdx.x) * 4;
    const int i0 = blockIdx.y * 32;
    for (int ii = 0; ii < 32; ++ii) {
        const int i = i0 + ii;
        const floatx4* p = reinterpret_cast<const floatx4*>(A + (size_t)i * N_NODES + jbase);
        floatx4 v = __builtin_nontemporal_load(p);
        if (v.x != 0.0f) { int q = atomicAdd(&col_cnt[jbase + 0], 1); if (q < CAP) col_idx[(size_t)(jbase + 0) * CAP + q] = i; }
        if (v.y != 0.0f) { int q = atomicAdd(&col_cnt[jbase + 1], 1); if (q < CAP) col_idx[(size_t)(jbase + 1) * CAP + q] = i; }
        if (v.z != 0.0f) { int q = atomicAdd(&col_cnt[jbase + 2], 1); if (q < CAP) col_idx[(size_t)(jbase + 2) * CAP + q] = i; }
        if (v.w != 0.0f) { int q = atomicAdd(&col_cnt[jbase + 3], 1); if (q < CAP) col_idx[(size_t)(jbase + 3) * CAP + q] = i; }
    }
}

// K2: per-edge weights w[j][e] = rsqrt(deg[idx]+1).
__global__ __launch_bounds__(128) void fill_w(const int* __restrict__ col_idx,
                                              const int* __restrict__ col_cnt,
                                              float* __restrict__ w) {
    const int j = blockIdx.x, e = threadIdx.x;
    if (e < min(col_cnt[j], CAP))
        w[(size_t)j * CAP + e] = rsqrtf((float)col_cnt[col_idx[(size_t)j * CAP + e]] + 1.0f);
}

// K3 (fused): bf16 copy of x (gather source, 4 MB) + transpose/split weights.
__global__ __launch_bounds__(256) void prep_misc(const float* __restrict__ x,
                                                 const float* __restrict__ W1,
                                                 const float* __restrict__ W2,
                                                 ushort* __restrict__ xb,
                                                 ushort* __restrict__ W1Th, ushort* __restrict__ W1Tl,
                                                 ushort* __restrict__ W2Th, ushort* __restrict__ W2Tl) {
    const int idx = blockIdx.x * 256 + threadIdx.x;   // < 524288
    {
        const int i = idx * 4;
        const floatx4 v = *reinterpret_cast<const floatx4*>(x + i);
        *reinterpret_cast<ushort4*>(xb + i) = ushort4{f2bf(v.x), f2bf(v.y), f2bf(v.z), f2bf(v.w)};
    }
    if (idx < IN_DIM * HID) {
        {
            const int k = idx / HID, n = idx % HID;
            const float v = W1[idx]; const ushort h = f2bf(v);
            W1Th[(size_t)n * IN_DIM + k] = h;
            W1Tl[(size_t)n * IN_DIM + k] = f2bf(v - bf2f(h));
        }
        {
            const int k = idx / NCLS, n = idx % NCLS;
            const float v = W2[idx]; const ushort h = f2bf(v);
            W2Th[(size_t)n * HID + k] = h;
            W2Tl[(size_t)n * HID + k] = f2bf(v - bf2f(h));
        }
    }
}

// ---------------------------------------------------------------------------
// K4: layer-1 aggregation over bf16 x rows (P commutes with the GEMM).
// Wave-per-node, lane owns 4 feats (uint2 = 8 B; 64 lanes = one 512 B row
// per load). 8-deep edge unroll. Node index wave-uniform -> idx/w scalarize.
// px -> split bf16 (GEMM1 A-operand).
// ---------------------------------------------------------------------------
__global__ __launch_bounds__(256) void agg_x(const ushort* __restrict__ xb,
                                             const int* __restrict__ col_idx,
                                             const int* __restrict__ col_cnt,
                                             const float* __restrict__ w,
                                             ushort* __restrict__ px_hi,
                                             ushort* __restrict__ px_lo) {
    const int j = __builtin_amdgcn_readfirstlane(blockIdx.x * 4 + (threadIdx.x >> 6));
    const int d = (threadIdx.x & 63) * 4;
    const int cntr = col_cnt[j];
    const int cnt = min(cntr, CAP);
    const float dj = rsqrtf((float)cntr + 1.0f);
    float a0, a1, a2, a3;
    {
        const uint2 sv = *reinterpret_cast<const uint2*>(xb + (size_t)j * IN_DIM + d);
        float f0, f1, f2, f3;
        bfpair(sv.x, f0, f1); bfpair(sv.y, f2, f3);
        a0 = dj * f0; a1 = dj * f1; a2 = dj * f2; a3 = dj * f3;
    }
    const int*   __restrict__ lst = col_idx + (size_t)j * CAP;
    const float* __restrict__ wl  = w       + (size_t)j * CAP;
    int e = 0;
    for (; e + 8 <= cnt; e += 8) {
        uint2 rv[8]; float we[8];
#pragma unroll
        for (int q = 0; q < 8; ++q) {
            rv[q] = *reinterpret_cast<const uint2*>(xb + (size_t)lst[e + q] * IN_DIM + d);
            we[q] = wl[e + q];
        }
#pragma unroll
        for (int q = 0; q < 8; ++q) {
            float f0, f1, f2, f3;
            bfpair(rv[q].x, f0, f1); bfpair(rv[q].y, f2, f3);
            a0 += we[q] * f0; a1 += we[q] * f1; a2 += we[q] * f2; a3 += we[q] * f3;
        }
    }
    for (; e < cnt; ++e) {
        const uint2 rv = *reinterpret_cast<const uint2*>(xb + (size_t)lst[e] * IN_DIM + d);
        const float we = wl[e];
        float f0, f1, f2, f3;
        bfpair(rv.x, f0, f1); bfpair(rv.y, f2, f3);
        a0 += we * f0; a1 += we * f1; a2 += we * f2; a3 += we * f3;
    }
    a0 *= dj; a1 *= dj; a2 *= dj; a3 *= dj;
    const ushort h0 = f2bf(a0), h1 = f2bf(a1), h2 = f2bf(a2), h3 = f2bf(a3);
    *reinterpret_cast<ushort4*>(px_hi + (size_t)j * IN_DIM + d) = ushort4{h0, h1, h2, h3};
    *reinterpret_cast<ushort4*>(px_lo + (size_t)j * IN_DIM + d) =
        ushort4{f2bf(a0 - bf2f(h0)), f2bf(a1 - bf2f(h1)), f2bf(a2 - bf2f(h2)), f2bf(a3 - bf2f(h3))};
}

// ---------------------------------------------------------------------------
// Shared GEMM core: acc[4][2] += (Ah+Al)[M,K] @ (Bh+Bl)[N,K]^T, split-bf16
// 3-product. 16x16x32 MFMA. Block = 4 waves (2Mx2N), block tile 128x64.
// K compile-time -> unroll 2 pipelines next step's 12 fragment loads under
// the current step's 24 MFMAs.
// ---------------------------------------------------------------------------
template<int K>
__device__ __forceinline__ void gemm_core(const ushort* __restrict__ Ah,
                                          const ushort* __restrict__ Al,
                                          const ushort* __restrict__ Bh,
                                          const ushort* __restrict__ Bl,
                                          int m_base, int n_base,
                                          int l16, int quad, floatx4 acc[4][2]) {
#pragma unroll 2
    for (int k0 = 0; k0 < K; k0 += 32) {
        const int kf = k0 + quad * 8;
        bf16x8 ah[4], al[4], bh[2], bl[2];
#pragma unroll
        for (int t = 0; t < 4; ++t) {
            const size_t ao = (size_t)(m_base + t * 16 + l16) * K + kf;
            ah[t] = *reinterpret_cast<const bf16x8*>(Ah + ao);
            al[t] = *reinterpret_cast<const bf16x8*>(Al + ao);
        }
#pragma unroll
        for (int t = 0; t < 2; ++t) {
            const size_t bo = (size_t)(n_base + t * 16 + l16) * K + kf;
            bh[t] = *reinterpret_cast<const bf16x8*>(Bh + bo);
            bl[t] = *reinterpret_cast<const bf16x8*>(Bl + bo);
        }
#pragma unroll
        for (int tm = 0; tm < 4; ++tm)
#pragma unroll
            for (int tn = 0; tn < 2; ++tn) {
                acc[tm][tn] = __builtin_amdgcn_mfma_f32_16x16x32_bf16(ah[tm], bl[tn], acc[tm][tn], 0, 0, 0);
                acc[tm][tn] = __builtin_amdgcn_mfma_f32_16x16x32_bf16(al[tm], bh[tn], acc[tm][tn], 0, 0, 0);
                acc[tm][tn] = __builtin_amdgcn_mfma_f32_16x16x32_bf16(ah[tm], bh[tn], acc[tm][tn], 0, 0, 0);
            }
    }
}

// K5: h = relu(px @ W1 + b1) -> split bf16 (GEMM2 operand).
__global__ __launch_bounds__(256) void gemm1_fused(const ushort* __restrict__ Ah,
                                                   const ushort* __restrict__ Al,
                                                   const ushort* __restrict__ Bh,
                                                   const ushort* __restrict__ Bl,
                                                   const float* __restrict__ b1,
                                                   ushort* __restrict__ h_hi,
                                                   ushort* __restrict__ h_lo) {
    const int tid = threadIdx.x;
    const int lane = tid & 63, wave = tid >> 6;
    const int wm = wave >> 1, wn = wave & 1;
    const int l16 = lane & 15, quad = lane >> 4;
    const int m_base = blockIdx.x * 128 + wm * 64;
    const int n_base = blockIdx.y * 64 + wn * 32;
    floatx4 acc[4][2] = {};
    gemm_core<IN_DIM>(Ah, Al, Bh, Bl, m_base, n_base, l16, quad, acc);
#pragma unroll
    for (int tn = 0; tn < 2; ++tn) {
        const int col = n_base + tn * 16 + l16;
        const float bv = b1[col];
#pragma unroll
        for (int tm = 0; tm < 4; ++tm)
#pragma unroll
            for (int r = 0; r < 4; ++r) {
                const int row = m_base + tm * 16 + quad * 4 + r;
                const float v = fmaxf(acc[tm][tn][r] + bv, 0.0f);
                const ushort hi = f2bf(v);
                h_hi[(size_t)row * HID + col] = hi;
                h_lo[(size_t)row * HID + col] = f2bf(v - bf2f(hi));
            }
    }
}

// K6: g2 = h @ W2, written bf16 (4 MB gather source; post-aggregation
// rounding ~3e-4, negligible vs 2e-2 threshold).
__global__ __launch_bounds__(256) void gemm2(const ushort* __restrict__ Ah,
                                             const ushort* __restrict__ Al,
                                             const ushort* __restrict__ Bh,
                                             const ushort* __restrict__ Bl,
                                             ushort* __restrict__ g2b) {
    const int tid = threadIdx.x;
    const int lane = tid & 63, wave = tid >> 6;
    const int wm = wave >> 1, wn = wave & 1;
    const int l16 = lane & 15, quad = lane >> 4;
    const int m_base = blockIdx.x * 128 + wm * 64;
    const int n_base = blockIdx.y * 64 + wn * 32;
    floatx4 acc[4][2] = {};
    gemm_core<HID>(Ah, Al, Bh, Bl, m_base, n_base, l16, quad, acc);
#pragma unroll
    for (int tm = 0; tm < 4; ++tm)
#pragma unroll
        for (int tn = 0; tn < 2; ++tn)
#pragma unroll
            for (int r = 0; r < 4; ++r)
                g2b[(size_t)(m_base + tm * 16 + quad * 4 + r) * NCLS + (n_base + tn * 16 + l16)] =
                    f2bf(acc[tm][tn][r]);
}

// ---------------------------------------------------------------------------
// K7: layer-2 aggregation over bf16 g2 rows + bias + skip + scaled sigmoid.
// x skip-read and out store are nontemporal (touched exactly once).
// ---------------------------------------------------------------------------
__global__ __launch_bounds__(256) void agg_out(const ushort* __restrict__ g2b,
                                               const int* __restrict__ col_idx,
                                               const int* __restrict__ col_cnt,
                                               const float* __restrict__ w,
                                               const float* __restrict__ b2,
                                               const float* __restrict__ x,
                                               const float* __restrict__ sp_p,
                                               float* __restrict__ out) {
    const int j = __builtin_amdgcn_readfirstlane(blockIdx.x * 4 + (threadIdx.x >> 6));
    const int d = (threadIdx.x & 63) * 4;
    const int cntr = col_cnt[j];
    const int cnt = min(cntr, CAP);
    const float dj = rsqrtf((float)cntr + 1.0f);
    float a0, a1, a2, a3;
    {
        const uint2 sv = *reinterpret_cast<const uint2*>(g2b + (size_t)j * NCLS + d);
        float f0, f1, f2, f3;
        bfpair(sv.x, f0, f1); bfpair(sv.y, f2, f3);
        a0 = dj * f0; a1 = dj * f1; a2 = dj * f2; a3 = dj * f3;
    }
    const int*   __restrict__ lst = col_idx + (size_t)j * CAP;
    const float* __restrict__ wl  = w       + (size_t)j * CAP;
    int e = 0;
    for (; e + 8 <= cnt; e += 8) {
        uint2 rv[8]; float we[8];
#pragma unroll
        for (int q = 0; q < 8; ++q) {
            rv[q] = *reinterpret_cast<const uint2*>(g2b + (size_t)lst[e + q] * NCLS + d);
            we[q] = wl[e + q];
        }
#pragma unroll
        for (int q = 0; q < 8; ++q) {
            float f0, f1, f2, f3;
            bfpair(rv[q].x, f0, f1); bfpair(rv[q].y, f2, f3);
            a0 += we[q] * f0; a1 += we[q] * f1; a2 += we[q] * f2; a3 += we[q] * f3;
        }
    }
    for (; e < cnt; ++e) {
        const uint2 rv = *reinterpret_cast<const uint2*>(g2b + (size_t)lst[e] * NCLS + d);
        const float we = wl[e];
        float f0, f1, f2, f3;
        bfpair(rv.x, f0, f1); bfpair(rv.y, f2, f3);
        a0 += we * f0; a1 += we * f1; a2 += we * f2; a3 += we * f3;
    }
    const float sp = sp_p[0];
    const floatx4 bv = *reinterpret_cast<const floatx4*>(b2 + d);
    const floatx4 xv = __builtin_nontemporal_load(
        reinterpret_cast<const floatx4*>(x + (size_t)j * NCLS + d));
    floatx4 o;
    o.x = 1.0f / (1.0f + __expf(-sp * (dj * a0 + bv.x + xv.x)));
    o.y = 1.0f / (1.0f + __expf(-sp * (dj * a1 + bv.y + xv.y)));
    o.z = 1.0f / (1.0f + __expf(-sp * (dj * a2 + bv.z + xv.z)));
    o.w = 1.0f / (1.0f + __expf(-sp * (dj * a3 + bv.w + xv.w)));
    __builtin_nontemporal_store(o, reinterpret_cast<floatx4*>(out + (size_t)j * NCLS + d));
}

extern "C" void kernel_launch(void* const* d_in, const int* in_sizes, int n_in,
                              void* d_out, int out_size, void* d_ws, size_t ws_size,
                              hipStream_t stream) {
    const float* A  = (const float*)d_in[0];   // [8192,8192] fp32 (0.0/1.0)
    const float* x  = (const float*)d_in[1];   // [8192,256]  fp32
    const float* W1 = (const float*)d_in[2];   // [256,512]   fp32
    const float* b1 = (const float*)d_in[3];   // [512]       fp32
    const float* W2 = (const float*)d_in[4];   // [512,256]   fp32
    const float* b2 = (const float*)d_in[5];   // [256]       fp32
    const float* sp = (const float*)d_in[6];   // [1]         fp32
    float* out = (float*)d_out;                // [8192,256]  fp32

    char* ws = (char*)d_ws;
    size_t off = 0;
    auto alloc = [&](size_t bytes) {
        void* p = ws + off;
        off = (off + bytes + 255) & ~(size_t)255;
        return p;
    };
    int*    col_cnt = (int*)   alloc((size_t)N_NODES * 4);
    int*    col_idx = (int*)   alloc((size_t)N_NODES * CAP * 4);     // 4 MB
    float*  wedge   = (float*) alloc((size_t)N_NODES * CAP * 4);     // 4 MB
    ushort* xb      = (ushort*)alloc((size_t)N_NODES * IN_DIM * 2);  // 4 MB
    ushort* px_hi   = (ushort*)alloc((size_t)N_NODES * IN_DIM * 2);  // 4 MB
    ushort* px_lo   = (ushort*)alloc((size_t)N_NODES * IN_DIM * 2);  // 4 MB
    ushort* W1Th    = (ushort*)alloc((size_t)HID * IN_DIM * 2);
    ushort* W1Tl    = (ushort*)alloc((size_t)HID * IN_DIM * 2);
    ushort* W2Th    = (ushort*)alloc((size_t)NCLS * HID * 2);
    ushort* W2Tl    = (ushort*)alloc((size_t)NCLS * HID * 2);
    ushort* h_hi    = (ushort*)alloc((size_t)N_NODES * HID * 2);     // 8 MB
    ushort* h_lo    = (ushort*)alloc((size_t)N_NODES * HID * 2);     // 8 MB
    ushort* g2b     = (ushort*)alloc((size_t)N_NODES * NCLS * 2);    // 4 MB

    (void)hipMemsetAsync(col_cnt, 0, (size_t)N_NODES * 4, stream);

    build_csc<<<dim3(8, 256), 256, 0, stream>>>(A, col_cnt, col_idx);
    prep_misc<<<(N_NODES * IN_DIM / 4) / 256, 256, 0, stream>>>(
        x, W1, W2, xb, W1Th, W1Tl, W2Th, W2Tl);
    fill_w<<<N_NODES, 128, 0, stream>>>(col_idx, col_cnt, wedge);

    // Layer 1: aggregate bf16 x first, then split-GEMM + relu.
    agg_x<<<N_NODES / 4, 256, 0, stream>>>(xb, col_idx, col_cnt, wedge, px_hi, px_lo);
    gemm1_fused<<<dim3(N_NODES / 128, HID / 64), 256, 0, stream>>>(
        px_hi, px_lo, W1Th, W1Tl, b1, h_hi, h_lo);

    // Layer 2: GEMM to bf16 g2, then aggregate + epilogue.
    gemm2<<<dim3(N_NODES / 128, NCLS / 64), 256, 0, stream>>>(
        h_hi, h_lo, W2Th, W2Tl, g2b);
    agg_out<<<N_NODES / 4, 256, 0, stream>>>(g2b, col_idx, col_cnt, wedge, b2, x, sp, out);
}

// Round 8
// 434.243 us; speedup vs baseline: 1.3551x; 1.0599x over previous
//
#include <hip/hip_runtime.h>
#include <hip/hip_bf16.h>

#define N_NODES 8192
#define IN_DIM  256
#define HID     512
#define NCLS    256
#define CAP     128   // max in-degree capacity (Poisson mean 32; max over 8192 draws ~56)

typedef __attribute__((ext_vector_type(8))) __bf16 bf16x8;
typedef __attribute__((ext_vector_type(4))) float  floatx4;   // native clang vector: ok for nontemporal builtins

static __device__ __forceinline__ float bf2f(ushort u) {
    union { float f; unsigned int i; } v; v.i = ((unsigned int)u) << 16; return v.f;
}
static __device__ __forceinline__ ushort f2bf(float f) {
    __hip_bfloat16 b = __float2bfloat16(f);   // round-to-nearest
    return *reinterpret_cast<ushort*>(&b);
}
// unpack one uint holding two packed bf16 (little-endian: lo ushort = element d)
static __device__ __forceinline__ void bfpair(unsigned int u, float& lo, float& hi) {
    union { float f; unsigned int i; } a, b;
    a.i = u << 16; b.i = u & 0xFFFF0000u;
    lo = a.f; hi = b.f;
}

// ---------------------------------------------------------------------------
// K1: scan A (fp32 binary, row-major [i][j]) -> per-column neighbor lists
// (ushort indices). Nontemporal 16B loads (A read exactly once; don't evict
// the gather sources). HBM-bound: 256 MB ~ 41 us floor.
// ---------------------------------------------------------------------------
__global__ __launch_bounds__(256) void build_csc(const float* __restrict__ A,
                                                 int* __restrict__ col_cnt,
                                                 ushort* __restrict__ col_idx) {
    const int jbase = (blockIdx.x * 256 + threadIdx.x) * 4;
    const int i0 = blockIdx.y * 32;
    for (int ii = 0; ii < 32; ++ii) {
        const int i = i0 + ii;
        const floatx4* p = reinterpret_cast<const floatx4*>(A + (size_t)i * N_NODES + jbase);
        floatx4 v = __builtin_nontemporal_load(p);
        if (v.x != 0.0f) { int q = atomicAdd(&col_cnt[jbase + 0], 1); if (q < CAP) col_idx[(size_t)(jbase + 0) * CAP + q] = (ushort)i; }
        if (v.y != 0.0f) { int q = atomicAdd(&col_cnt[jbase + 1], 1); if (q < CAP) col_idx[(size_t)(jbase + 1) * CAP + q] = (ushort)i; }
        if (v.z != 0.0f) { int q = atomicAdd(&col_cnt[jbase + 2], 1); if (q < CAP) col_idx[(size_t)(jbase + 2) * CAP + q] = (ushort)i; }
        if (v.w != 0.0f) { int q = atomicAdd(&col_cnt[jbase + 3], 1); if (q < CAP) col_idx[(size_t)(jbase + 3) * CAP + q] = (ushort)i; }
    }
}

// ---------------------------------------------------------------------------
// K2 (fused): bf16 copy of x (gather source, 4 MB) + transpose/split weights
// + dis[j] = rsqrt(deg_j+1) (32 KB, stays L2-hot for the agg loops).
// Must run after build_csc (reads col_cnt).
// ---------------------------------------------------------------------------
__global__ __launch_bounds__(256) void prep_misc(const float* __restrict__ x,
                                                 const float* __restrict__ W1,
                                                 const float* __restrict__ W2,
                                                 const int* __restrict__ col_cnt,
                                                 ushort* __restrict__ xb,
                                                 float* __restrict__ dis,
                                                 ushort* __restrict__ W1Th, ushort* __restrict__ W1Tl,
                                                 ushort* __restrict__ W2Th, ushort* __restrict__ W2Tl) {
    const int idx = blockIdx.x * 256 + threadIdx.x;   // < 524288
    {
        const int i = idx * 4;
        const floatx4 v = *reinterpret_cast<const floatx4*>(x + i);
        *reinterpret_cast<ushort4*>(xb + i) = ushort4{f2bf(v.x), f2bf(v.y), f2bf(v.z), f2bf(v.w)};
    }
    if (idx < N_NODES)
        dis[idx] = rsqrtf((float)col_cnt[idx] + 1.0f);
    if (idx < IN_DIM * HID) {
        {
            const int k = idx / HID, n = idx % HID;
            const float v = W1[idx]; const ushort h = f2bf(v);
            W1Th[(size_t)n * IN_DIM + k] = h;
            W1Tl[(size_t)n * IN_DIM + k] = f2bf(v - bf2f(h));
        }
        {
            const int k = idx / NCLS, n = idx % NCLS;
            const float v = W2[idx]; const ushort h = f2bf(v);
            W2Th[(size_t)n * HID + k] = h;
            W2Tl[(size_t)n * HID + k] = f2bf(v - bf2f(h));
        }
    }
}

// ---------------------------------------------------------------------------
// K3: layer-1 aggregation over bf16 x rows (P commutes with the GEMM).
// Wave-per-node, lane owns 4 feats. 8-deep edge unroll; node index
// wave-uniform -> idx/dis loads scalarize. px -> single bf16 (GEMM1 A).
// ---------------------------------------------------------------------------
__global__ __launch_bounds__(256) void agg_x(const ushort* __restrict__ xb,
                                             const ushort* __restrict__ col_idx,
                                             const int* __restrict__ col_cnt,
                                             const float* __restrict__ dis,
                                             ushort* __restrict__ px) {
    const int j = __builtin_amdgcn_readfirstlane(blockIdx.x * 4 + (threadIdx.x >> 6));
    const int d = (threadIdx.x & 63) * 4;
    const int cnt = min(col_cnt[j], CAP);
    const float dj = dis[j];
    float a0, a1, a2, a3;
    {
        const uint2 sv = *reinterpret_cast<const uint2*>(xb + (size_t)j * IN_DIM + d);
        float f0, f1, f2, f3;
        bfpair(sv.x, f0, f1); bfpair(sv.y, f2, f3);
        a0 = dj * f0; a1 = dj * f1; a2 = dj * f2; a3 = dj * f3;
    }
    const ushort* __restrict__ lst = col_idx + (size_t)j * CAP;
    int e = 0;
    for (; e + 8 <= cnt; e += 8) {
        uint2 rv[8]; float we[8];
#pragma unroll
        for (int q = 0; q < 8; ++q) {
            const int i = lst[e + q];
            rv[q] = *reinterpret_cast<const uint2*>(xb + (size_t)i * IN_DIM + d);
            we[q] = dis[i];
        }
#pragma unroll
        for (int q = 0; q < 8; ++q) {
            float f0, f1, f2, f3;
            bfpair(rv[q].x, f0, f1); bfpair(rv[q].y, f2, f3);
            a0 += we[q] * f0; a1 += we[q] * f1; a2 += we[q] * f2; a3 += we[q] * f3;
        }
    }
    for (; e < cnt; ++e) {
        const int i = lst[e];
        const uint2 rv = *reinterpret_cast<const uint2*>(xb + (size_t)i * IN_DIM + d);
        const float we = dis[i];
        float f0, f1, f2, f3;
        bfpair(rv.x, f0, f1); bfpair(rv.y, f2, f3);
        a0 += we * f0; a1 += we * f1; a2 += we * f2; a3 += we * f3;
    }
    a0 *= dj; a1 *= dj; a2 *= dj; a3 *= dj;
    *reinterpret_cast<ushort4*>(px + (size_t)j * IN_DIM + d) =
        ushort4{f2bf(a0), f2bf(a1), f2bf(a2), f2bf(a3)};
}

// ---------------------------------------------------------------------------
// GEMM core: acc[4][4] += A[M,K](bf16) @ (Bh+Bl)[N,K]^T (split-bf16 weights,
// 2-product: A@Bh + A@Bl). 16x16x32 MFMA. Block = 4 waves (2Mx2N), wave tile
// 64x64, block tile 128x128 (fewer grid.y tiles -> less A re-read traffic).
// ---------------------------------------------------------------------------
template<int K>
__device__ __forceinline__ void gemm_core(const ushort* __restrict__ A,
                                          const ushort* __restrict__ Bh,
                                          const ushort* __restrict__ Bl,
                                          int m_base, int n_base,
                                          int l16, int quad, floatx4 acc[4][4]) {
#pragma unroll 2
    for (int k0 = 0; k0 < K; k0 += 32) {
        const int kf = k0 + quad * 8;
        bf16x8 a[4], bh[4], bl[4];
#pragma unroll
        for (int t = 0; t < 4; ++t)
            a[t] = *reinterpret_cast<const bf16x8*>(A + (size_t)(m_base + t * 16 + l16) * K + kf);
#pragma unroll
        for (int t = 0; t < 4; ++t) {
            const size_t bo = (size_t)(n_base + t * 16 + l16) * K + kf;
            bh[t] = *reinterpret_cast<const bf16x8*>(Bh + bo);
            bl[t] = *reinterpret_cast<const bf16x8*>(Bl + bo);
        }
#pragma unroll
        for (int tm = 0; tm < 4; ++tm)
#pragma unroll
            for (int tn = 0; tn < 4; ++tn) {
                acc[tm][tn] = __builtin_amdgcn_mfma_f32_16x16x32_bf16(a[tm], bl[tn], acc[tm][tn], 0, 0, 0);
                acc[tm][tn] = __builtin_amdgcn_mfma_f32_16x16x32_bf16(a[tm], bh[tn], acc[tm][tn], 0, 0, 0);
            }
    }
}

// K4: h = relu(px @ W1 + b1) -> bf16 (GEMM2 A-operand).
__global__ __launch_bounds__(256) void gemm1_fused(const ushort* __restrict__ A,
                                                   const ushort* __restrict__ Bh,
                                                   const ushort* __restrict__ Bl,
                                                   const float* __restrict__ b1,
                                                   ushort* __restrict__ h) {
    const int tid = threadIdx.x;
    const int lane = tid & 63, wave = tid >> 6;
    const int wm = wave >> 1, wn = wave & 1;
    const int l16 = lane & 15, quad = lane >> 4;
    const int m_base = blockIdx.x * 128 + wm * 64;
    const int n_base = blockIdx.y * 128 + wn * 64;
    floatx4 acc[4][4] = {};
    gemm_core<IN_DIM>(A, Bh, Bl, m_base, n_base, l16, quad, acc);
#pragma unroll
    for (int tn = 0; tn < 4; ++tn) {
        const int col = n_base + tn * 16 + l16;
        const float bv = b1[col];
#pragma unroll
        for (int tm = 0; tm < 4; ++tm)
#pragma unroll
            for (int r = 0; r < 4; ++r) {
                const int row = m_base + tm * 16 + quad * 4 + r;
                h[(size_t)row * HID + col] = f2bf(fmaxf(acc[tm][tn][r] + bv, 0.0f));
            }
    }
}

// K5: g2 = h @ W2 -> bf16 (4 MB gather source for agg_out).
__global__ __launch_bounds__(256) void gemm2(const ushort* __restrict__ A,
                                             const ushort* __restrict__ Bh,
                                             const ushort* __restrict__ Bl,
                                             ushort* __restrict__ g2b) {
    const int tid = threadIdx.x;
    const int lane = tid & 63, wave = tid >> 6;
    const int wm = wave >> 1, wn = wave & 1;
    const int l16 = lane & 15, quad = lane >> 4;
    const int m_base = blockIdx.x * 128 + wm * 64;
    const int n_base = blockIdx.y * 128 + wn * 64;
    floatx4 acc[4][4] = {};
    gemm_core<HID>(A, Bh, Bl, m_base, n_base, l16, quad, acc);
#pragma unroll
    for (int tm = 0; tm < 4; ++tm)
#pragma unroll
        for (int tn = 0; tn < 4; ++tn)
#pragma unroll
            for (int r = 0; r < 4; ++r)
                g2b[(size_t)(m_base + tm * 16 + quad * 4 + r) * NCLS + (n_base + tn * 16 + l16)] =
                    f2bf(acc[tm][tn][r]);
}

// ---------------------------------------------------------------------------
// K6: layer-2 aggregation over bf16 g2 rows + bias + skip + scaled sigmoid.
// x skip-read and out store are nontemporal (touched exactly once).
// ---------------------------------------------------------------------------
__global__ __launch_bounds__(256) void agg_out(const ushort* __restrict__ g2b,
                                               const ushort* __restrict__ col_idx,
                                               const int* __restrict__ col_cnt,
                                               const float* __restrict__ dis,
                                               const float* __restrict__ b2,
                                               const float* __restrict__ x,
                                               const float* __restrict__ sp_p,
                                               float* __restrict__ out) {
    const int j = __builtin_amdgcn_readfirstlane(blockIdx.x * 4 + (threadIdx.x >> 6));
    const int d = (threadIdx.x & 63) * 4;
    const int cnt = min(col_cnt[j], CAP);
    const float dj = dis[j];
    float a0, a1, a2, a3;
    {
        const uint2 sv = *reinterpret_cast<const uint2*>(g2b + (size_t)j * NCLS + d);
        float f0, f1, f2, f3;
        bfpair(sv.x, f0, f1); bfpair(sv.y, f2, f3);
        a0 = dj * f0; a1 = dj * f1; a2 = dj * f2; a3 = dj * f3;
    }
    const ushort* __restrict__ lst = col_idx + (size_t)j * CAP;
    int e = 0;
    for (; e + 8 <= cnt; e += 8) {
        uint2 rv[8]; float we[8];
#pragma unroll
        for (int q = 0; q < 8; ++q) {
            const int i = lst[e + q];
            rv[q] = *reinterpret_cast<const uint2*>(g2b + (size_t)i * NCLS + d);
            we[q] = dis[i];
        }
#pragma unroll
        for (int q = 0; q < 8; ++q) {
            float f0, f1, f2, f3;
            bfpair(rv[q].x, f0, f1); bfpair(rv[q].y, f2, f3);
            a0 += we[q] * f0; a1 += we[q] * f1; a2 += we[q] * f2; a3 += we[q] * f3;
        }
    }
    for (; e < cnt; ++e) {
        const int i = lst[e];
        const uint2 rv = *reinterpret_cast<const uint2*>(g2b + (size_t)i * NCLS + d);
        const float we = dis[i];
        float f0, f1, f2, f3;
        bfpair(rv.x, f0, f1); bfpair(rv.y, f2, f3);
        a0 += we * f0; a1 += we * f1; a2 += we * f2; a3 += we * f3;
    }
    const float sp = sp_p[0];
    const floatx4 bv = *reinterpret_cast<const floatx4*>(b2 + d);
    const floatx4 xv = __builtin_nontemporal_load(
        reinterpret_cast<const floatx4*>(x + (size_t)j * NCLS + d));
    floatx4 o;
    o.x = 1.0f / (1.0f + __expf(-sp * (dj * a0 + bv.x + xv.x)));
    o.y = 1.0f / (1.0f + __expf(-sp * (dj * a1 + bv.y + xv.y)));
    o.z = 1.0f / (1.0f + __expf(-sp * (dj * a2 + bv.z + xv.z)));
    o.w = 1.0f / (1.0f + __expf(-sp * (dj * a3 + bv.w + xv.w)));
    __builtin_nontemporal_store(o, reinterpret_cast<floatx4*>(out + (size_t)j * NCLS + d));
}

extern "C" void kernel_launch(void* const* d_in, const int* in_sizes, int n_in,
                              void* d_out, int out_size, void* d_ws, size_t ws_size,
                              hipStream_t stream) {
    const float* A  = (const float*)d_in[0];   // [8192,8192] fp32 (0.0/1.0)
    const float* x  = (const float*)d_in[1];   // [8192,256]  fp32
    const float* W1 = (const float*)d_in[2];   // [256,512]   fp32
    const float* b1 = (const float*)d_in[3];   // [512]       fp32
    const float* W2 = (const float*)d_in[4];   // [512,256]   fp32
    const float* b2 = (const float*)d_in[5];   // [256]       fp32
    const float* sp = (const float*)d_in[6];   // [1]         fp32
    float* out = (float*)d_out;                // [8192,256]  fp32

    char* ws = (char*)d_ws;
    size_t off = 0;
    auto alloc = [&](size_t bytes) {
        void* p = ws + off;
        off = (off + bytes + 255) & ~(size_t)255;
        return p;
    };
    int*    col_cnt = (int*)   alloc((size_t)N_NODES * 4);           // 32 KB
    float*  dis     = (float*) alloc((size_t)N_NODES * 4);           // 32 KB
    ushort* col_idx = (ushort*)alloc((size_t)N_NODES * CAP * 2);     // 2 MB
    ushort* xb      = (ushort*)alloc((size_t)N_NODES * IN_DIM * 2);  // 4 MB
    ushort* px      = (ushort*)alloc((size_t)N_NODES * IN_DIM * 2);  // 4 MB
    ushort* W1Th    = (ushort*)alloc((size_t)HID * IN_DIM * 2);
    ushort* W1Tl    = (ushort*)alloc((size_t)HID * IN_DIM * 2);
    ushort* W2Th    = (ushort*)alloc((size_t)NCLS * HID * 2);
    ushort* W2Tl    = (ushort*)alloc((size_t)NCLS * HID * 2);
    ushort* h       = (ushort*)alloc((size_t)N_NODES * HID * 2);     // 8 MB
    ushort* g2b     = (ushort*)alloc((size_t)N_NODES * NCLS * 2);    // 4 MB

    (void)hipMemsetAsync(col_cnt, 0, (size_t)N_NODES * 4, stream);

    build_csc<<<dim3(8, 256), 256, 0, stream>>>(A, col_cnt, col_idx);
    prep_misc<<<(N_NODES * IN_DIM / 4) / 256, 256, 0, stream>>>(
        x, W1, W2, col_cnt, xb, dis, W1Th, W1Tl, W2Th, W2Tl);

    // Layer 1: aggregate bf16 x first, then 2-product split-weight GEMM + relu.
    agg_x<<<N_NODES / 4, 256, 0, stream>>>(xb, col_idx, col_cnt, dis, px);
    gemm1_fused<<<dim3(N_NODES / 128, HID / 128), 256, 0, stream>>>(
        px, W1Th, W1Tl, b1, h);

    // Layer 2: GEMM to bf16 g2, then aggregate + epilogue.
    gemm2<<<dim3(N_NODES / 128, NCLS / 128), 256, 0, stream>>>(
        h, W2Th, W2Tl, g2b);
    agg_out<<<N_NODES / 4, 256, 0, stream>>>(g2b, col_idx, col_cnt, dis, b2, x, sp, out);
}